// Round 1
// baseline (760.397 us; speedup 1.0000x reference)
//
#include <hip/hip_runtime.h>
#include <cmath>

// InvariantPointAttention, N=768, H=12, D=16, NQP=4, NVP=8, NODE=384, EDGE=128.
// fp32 throughout. Multi-kernel baseline; edge_features (302 MB) read twice
// (k_logits, k_eout). All intermediates in d_ws (~42 MB).

namespace {

constexpr int NN = 768;
constexpr int NH = 12;

// logit = (ns + eb - dist)/sqrt(3)
//       = C1*<sq_i,sk_j> + C2*<gk_i,gq_j> - C3*(ksq_i + qsq_j) + S3*eb
// with ns = <sq,sk>/4, dist = (ksq_i + qsq_j - 2*cross)*wc, wc = sqrt(2/9/4)/2
constexpr float S3 = 0.5773502691896258f;        // 3^-0.5
constexpr float C1 = 0.25f * S3;                 // 0.144337567
constexpr float C2 = 0.23570226039551584f * S3;  // 2*wc/sqrt(3) = 0.136082763
constexpr float C3 = 0.11785113019775792f * S3;  // wc/sqrt(3)   = 0.068041382

// ---------------------------------------------------------------- k_proj ----
// proj[768][1152] = node[768][384] @ [Wqkv(576) | Wvqk(288) | Wvv(288)]
__global__ __launch_bounds__(384) void k_proj(const float* __restrict__ node,
    const float* __restrict__ Wqkv, const float* __restrict__ Wvqk,
    const float* __restrict__ Wvv, float* __restrict__ proj) {
  __shared__ __align__(16) float nl[8][384];
  const int i0 = blockIdx.x * 8;
  const int tid = threadIdx.x;
  for (int idx = tid; idx < 8 * 384; idx += 384)
    ((float*)nl)[idx] = node[(size_t)i0 * 384 + idx];
  __syncthreads();
  for (int cc = 0; cc < 3; ++cc) {
    const int c = tid + cc * 384;
    const float* W; int ld, col;
    if (c < 576)      { W = Wqkv; ld = 576; col = c; }
    else if (c < 864) { W = Wvqk; ld = 288; col = c - 576; }
    else              { W = Wvv;  ld = 288; col = c - 864; }
    float acc[8] = {0.f,0.f,0.f,0.f,0.f,0.f,0.f,0.f};
    for (int k4 = 0; k4 < 96; ++k4) {
      const int k = k4 * 4;
      const float w0 = W[(size_t)(k + 0) * ld + col];
      const float w1 = W[(size_t)(k + 1) * ld + col];
      const float w2 = W[(size_t)(k + 2) * ld + col];
      const float w3 = W[(size_t)(k + 3) * ld + col];
#pragma unroll
      for (int r = 0; r < 8; ++r) {
        const float4 nv = *(const float4*)&nl[r][k];
        acc[r] += nv.x * w0 + nv.y * w1 + nv.z * w2 + nv.w * w3;
      }
    }
#pragma unroll
    for (int r = 0; r < 8; ++r) proj[(size_t)(i0 + r) * 1152 + c] = acc[r];
  }
}

// ---------------------------------------------------------------- k_geom ----
// Per (n,h): split proj into sq/sk/sv, apply frames (R,t) to point projections,
// compute q_sq/k_sq, build V = [sv(16) | gvv(24)] per (h,j). Also transpose
// Webias[128][12] -> wbT[12][128].
__global__ __launch_bounds__(256) void k_geom(const float* __restrict__ proj,
    const float* __restrict__ R, const float* __restrict__ t,
    const float* __restrict__ Webias,
    float* __restrict__ sq, float* __restrict__ sk,
    float* __restrict__ gk, float* __restrict__ gq,
    float* __restrict__ ksq, float* __restrict__ qsq,
    float* __restrict__ wbT, float* __restrict__ V) {
  const int gid = blockIdx.x * 256 + threadIdx.x;
  if (gid < 128 * 12) {
    const int d = gid / 12, h = gid % 12;
    wbT[h * 128 + d] = Webias[gid];
  }
  if (gid >= NN * NH) return;
  const int n = gid / NH, h = gid % NH;
  const float* pr = proj + (size_t)n * 1152;
  const float* Rn = R + n * 9;
  const float t0 = t[n * 3 + 0], t1 = t[n * 3 + 1], t2 = t[n * 3 + 2];
  const size_t hn = (size_t)h * NN + n;
#pragma unroll
  for (int d = 0; d < 16; ++d) {
    sq[hn * 16 + d] = pr[h * 16 + d];            // qkv[...,0,h,d]
    sk[hn * 16 + d] = pr[(12 + h) * 16 + d];     // qkv[...,1,h,d]
    V[hn * 40 + d]  = pr[(24 + h) * 16 + d];     // sv = qkv[...,2,h,d]
  }
  float qs = 0.f, ks = 0.f;
#pragma unroll
  for (int p = 0; p < 4; ++p) {
    {  // vq -> gq
      const float vx = pr[576 + (h * 4 + p) * 3 + 0];
      const float vy = pr[576 + (h * 4 + p) * 3 + 1];
      const float vz = pr[576 + (h * 4 + p) * 3 + 2];
      const float g0 = Rn[0] * vx + Rn[1] * vy + Rn[2] * vz + t0;
      const float g1 = Rn[3] * vx + Rn[4] * vy + Rn[5] * vz + t1;
      const float g2 = Rn[6] * vx + Rn[7] * vy + Rn[8] * vz + t2;
      gq[hn * 12 + p * 3 + 0] = g0;
      gq[hn * 12 + p * 3 + 1] = g1;
      gq[hn * 12 + p * 3 + 2] = g2;
      qs += g0 * g0 + g1 * g1 + g2 * g2;
    }
    {  // vk -> gk
      const float vx = pr[576 + ((12 + h) * 4 + p) * 3 + 0];
      const float vy = pr[576 + ((12 + h) * 4 + p) * 3 + 1];
      const float vz = pr[576 + ((12 + h) * 4 + p) * 3 + 2];
      const float g0 = Rn[0] * vx + Rn[1] * vy + Rn[2] * vz + t0;
      const float g1 = Rn[3] * vx + Rn[4] * vy + Rn[5] * vz + t1;
      const float g2 = Rn[6] * vx + Rn[7] * vy + Rn[8] * vz + t2;
      gk[hn * 12 + p * 3 + 0] = g0;
      gk[hn * 12 + p * 3 + 1] = g1;
      gk[hn * 12 + p * 3 + 2] = g2;
      ks += g0 * g0 + g1 * g1 + g2 * g2;
    }
  }
  qsq[hn] = qs;
  ksq[hn] = ks;
#pragma unroll
  for (int p = 0; p < 8; ++p) {  // vv -> gvv
    const float vx = pr[864 + (h * 8 + p) * 3 + 0];
    const float vy = pr[864 + (h * 8 + p) * 3 + 1];
    const float vz = pr[864 + (h * 8 + p) * 3 + 2];
    V[hn * 40 + 16 + p * 3 + 0] = Rn[0] * vx + Rn[1] * vy + Rn[2] * vz + t0;
    V[hn * 40 + 16 + p * 3 + 1] = Rn[3] * vx + Rn[4] * vy + Rn[5] * vz + t1;
    V[hn * 40 + 16 + p * 3 + 2] = Rn[6] * vx + Rn[7] * vy + Rn[8] * vz + t2;
  }
}

// -------------------------------------------------------------- k_logits ----
// Full attention logits, one pass over edge. Block = (j-tile of 64, i).
// Thread: jj = tid&63 (one edge row), wave-uniform h-group of 3 heads.
// Webias rows are wave-uniform -> compiler emits scalar loads (no LDS at all).
__global__ __launch_bounds__(256) void k_logits(const float* __restrict__ edge,
    const float* __restrict__ wbT, const float* __restrict__ sq,
    const float* __restrict__ sk, const float* __restrict__ gk,
    const float* __restrict__ gq, const float* __restrict__ ksq,
    const float* __restrict__ qsq, float* __restrict__ logits) {
  const int i  = blockIdx.y;
  const int j0 = blockIdx.x * 64;
  const int jj = threadIdx.x & 63;
  const int hg = __builtin_amdgcn_readfirstlane((int)(threadIdx.x >> 6));  // 0..3
  const int j = j0 + jj;
  const float* erow = edge + ((size_t)i * NN + j) * 128;
  float eb[3] = {0.f, 0.f, 0.f};
  for (int d4 = 0; d4 < 32; ++d4) {
    const float4 e4 = *(const float4*)(erow + d4 * 4);
#pragma unroll
    for (int u = 0; u < 3; ++u) {
      const float4 w4 = *(const float4*)(wbT + (hg * 3 + u) * 128 + d4 * 4);
      eb[u] += e4.x * w4.x + e4.y * w4.y + e4.z * w4.z + e4.w * w4.w;
    }
  }
#pragma unroll
  for (int u = 0; u < 3; ++u) {
    const int h = hg * 3 + u;
    const float* sqp = sq + ((size_t)h * NN + i) * 16;  // wave-uniform
    const float* skp = sk + ((size_t)h * NN + j) * 16;
    float dsk = 0.f;
#pragma unroll
    for (int k4 = 0; k4 < 4; ++k4) {
      const float4 a = *(const float4*)(sqp + k4 * 4);
      const float4 b = *(const float4*)(skp + k4 * 4);
      dsk += a.x * b.x + a.y * b.y + a.z * b.z + a.w * b.w;
    }
    const float* gkp = gk + ((size_t)h * NN + i) * 12;  // wave-uniform
    const float* gqp = gq + ((size_t)h * NN + j) * 12;
    float dgq = 0.f;
#pragma unroll
    for (int k4 = 0; k4 < 3; ++k4) {
      const float4 a = *(const float4*)(gkp + k4 * 4);
      const float4 b = *(const float4*)(gqp + k4 * 4);
      dgq += a.x * b.x + a.y * b.y + a.z * b.z + a.w * b.w;
    }
    const float logit = C1 * dsk + C2 * dgq
                      - C3 * (ksq[(size_t)h * NN + i] + qsq[(size_t)h * NN + j])
                      + S3 * eb[u];
    logits[((size_t)h * NN + i) * NN + j] = logit;
  }
}

// ------------------------------------------------------------- k_softmax ----
// In-place row softmax over j; one block per (h,i) row of 768.
__global__ __launch_bounds__(256) void k_softmax(float* __restrict__ logits) {
  float* p = logits + (size_t)blockIdx.x * NN;
  const int tid = threadIdx.x;
  float v0 = p[tid], v1 = p[tid + 256], v2 = p[tid + 512];
  float m = fmaxf(v0, fmaxf(v1, v2));
#pragma unroll
  for (int off = 32; off > 0; off >>= 1) m = fmaxf(m, __shfl_xor(m, off, 64));
  __shared__ float redm[4];
  __shared__ float reds[4];
  const int wid = tid >> 6, lane = tid & 63;
  if (lane == 0) redm[wid] = m;
  __syncthreads();
  m = fmaxf(fmaxf(redm[0], redm[1]), fmaxf(redm[2], redm[3]));
  v0 = __expf(v0 - m); v1 = __expf(v1 - m); v2 = __expf(v2 - m);
  float s = v0 + v1 + v2;
#pragma unroll
  for (int off = 32; off > 0; off >>= 1) s += __shfl_xor(s, off, 64);
  if (lane == 0) reds[wid] = s;
  __syncthreads();
  s = reds[0] + reds[1] + reds[2] + reds[3];
  const float inv = 1.0f / s;
  p[tid] = v0 * inv; p[tid + 256] = v1 * inv; p[tid + 512] = v2 * inv;
}

// ---------------------------------------------------------------- k_eout ----
// edge_out[i][h*128+d] = sum_j attn[h,i,j] * edge[i,j,d].
// Block per i (192 thr = 3 waves). attn row staged transposed in LDS so the
// attn operand is one b128 broadcast per j. Thread tile: 4 heads x 2 d.
__global__ __launch_bounds__(192) void k_eout(const float* __restrict__ edge,
    const float* __restrict__ attn, float* __restrict__ eout) {
  const int i = blockIdx.x;
  const int tid = threadIdx.x;
  __shared__ __align__(16) float alT[768][16];  // [j][h], 48 KB
  for (int idx = tid; idx < NH * NN; idx += 192) {
    const int h = idx / NN, j = idx % NN;
    alT[j][h] = attn[((size_t)h * NN + i) * NN + j];
  }
  __syncthreads();
  const int h0 = (tid / 64) * 4;   // 0,4,8
  const int d0 = (tid % 64) * 2;   // 0..126
  const float* ebase = edge + (size_t)i * NN * 128 + d0;
  float a00 = 0.f, a01 = 0.f, a10 = 0.f, a11 = 0.f;
  float a20 = 0.f, a21 = 0.f, a30 = 0.f, a31 = 0.f;
  for (int j = 0; j < NN; ++j) {
    const float2 e2 = *(const float2*)(ebase + (size_t)j * 128);
    const float4 a4 = *(const float4*)&alT[j][h0];
    a00 += a4.x * e2.x; a01 += a4.x * e2.y;
    a10 += a4.y * e2.x; a11 += a4.y * e2.y;
    a20 += a4.z * e2.x; a21 += a4.z * e2.y;
    a30 += a4.w * e2.x; a31 += a4.w * e2.y;
  }
  float* op = eout + (size_t)i * 1536;
  op[(h0 + 0) * 128 + d0] = a00; op[(h0 + 0) * 128 + d0 + 1] = a01;
  op[(h0 + 1) * 128 + d0] = a10; op[(h0 + 1) * 128 + d0 + 1] = a11;
  op[(h0 + 2) * 128 + d0] = a20; op[(h0 + 2) * 128 + d0 + 1] = a21;
  op[(h0 + 3) * 128 + d0] = a30; op[(h0 + 3) * 128 + d0 + 1] = a31;
}

// ---------------------------------------------------------------- k_scav ----
// scav[h][i][0..39] = sum_j attn[h,i,j] * V[h][j][0..39]  (sv | gvv).
// Block per (64-row i-tile, h), 320 thr. Thread tile 4 rows x 2 cols.
// attn tile staged transposed -> one b128 read per j per thread.
__global__ __launch_bounds__(320) void k_scav(const float* __restrict__ attn,
    const float* __restrict__ V, float* __restrict__ scav) {
  const int i0 = blockIdx.x * 64;
  const int h  = blockIdx.y;
  const int tid = threadIdx.x;
  const int r0 = (tid / 20) * 4;  // 0..60
  const int c0 = (tid % 20) * 2;  // 0..38
  __shared__ __align__(16) float At[64][68];  // [jj][r]
  float acc[4][2] = {{0.f,0.f},{0.f,0.f},{0.f,0.f},{0.f,0.f}};
  for (int jt = 0; jt < 12; ++jt) {
    const int j0 = jt * 64;
    __syncthreads();
    for (int idx = tid; idx < 64 * 64; idx += 320) {
      const int r = idx / 64, jj = idx % 64;
      At[jj][r] = attn[((size_t)h * NN + i0 + r) * NN + j0 + jj];
    }
    __syncthreads();
    for (int jj = 0; jj < 64; ++jj) {
      const float4 a4 = *(const float4*)&At[jj][r0];
      const float2 b2 = *(const float2*)(V + ((size_t)h * NN + j0 + jj) * 40 + c0);
      acc[0][0] += a4.x * b2.x; acc[0][1] += a4.x * b2.y;
      acc[1][0] += a4.y * b2.x; acc[1][1] += a4.y * b2.y;
      acc[2][0] += a4.z * b2.x; acc[2][1] += a4.z * b2.y;
      acc[3][0] += a4.w * b2.x; acc[3][1] += a4.w * b2.y;
    }
  }
#pragma unroll
  for (int u = 0; u < 4; ++u)
#pragma unroll
    for (int v = 0; v < 2; ++v)
      scav[((size_t)h * NN + i0 + r0 + u) * 40 + c0 + v] = acc[u][v];
}

// --------------------------------------------------------------- k_final ----
// Per 4 rows: Rinv (adjugate), local_v, v_len, concat to combined[2112] in LDS,
// then out = node + combined @ Wfin + bfin.
__global__ __launch_bounds__(256) void k_final(const float* __restrict__ node,
    const float* __restrict__ R, const float* __restrict__ t,
    const float* __restrict__ eout, const float* __restrict__ scav,
    const float* __restrict__ Wfin, const float* __restrict__ bfin,
    float* __restrict__ out) {
  const int i0 = blockIdx.x * 4;
  const int tid = threadIdx.x;
  __shared__ __align__(16) float comb[4][2112];
  __shared__ float rinv[4][9];
  __shared__ float tl[4][3];
  if (tid < 4) {
    const int i = i0 + tid;
    const float* Rn = R + i * 9;
    const float r00 = Rn[0], r01 = Rn[1], r02 = Rn[2];
    const float r10 = Rn[3], r11 = Rn[4], r12 = Rn[5];
    const float r20 = Rn[6], r21 = Rn[7], r22 = Rn[8];
    const float det = r00 * (r11 * r22 - r12 * r21)
                    - r01 * (r10 * r22 - r12 * r20)
                    + r02 * (r10 * r21 - r11 * r20);
    const float id = 1.0f / det;
    rinv[tid][0] = (r11 * r22 - r12 * r21) * id;
    rinv[tid][1] = (r02 * r21 - r01 * r22) * id;
    rinv[tid][2] = (r01 * r12 - r02 * r11) * id;
    rinv[tid][3] = (r12 * r20 - r10 * r22) * id;
    rinv[tid][4] = (r00 * r22 - r02 * r20) * id;
    rinv[tid][5] = (r02 * r10 - r00 * r12) * id;
    rinv[tid][6] = (r10 * r21 - r11 * r20) * id;
    rinv[tid][7] = (r01 * r20 - r00 * r21) * id;
    rinv[tid][8] = (r00 * r11 - r01 * r10) * id;
    tl[tid][0] = t[i * 3 + 0]; tl[tid][1] = t[i * 3 + 1]; tl[tid][2] = t[i * 3 + 2];
  }
  __syncthreads();
  for (int idx = tid; idx < 4 * 2112; idx += 256) {
    const int r = idx / 2112, k = idx % 2112;
    const int i = i0 + r;
    float val;
    if (k < 1536) {                     // edge_out
      val = eout[(size_t)i * 1536 + k];
    } else if (k < 1728) {              // scalar_out
      const int s = k - 1536, h = s >> 4, d = s & 15;
      val = scav[((size_t)h * NN + i) * 40 + d];
    } else if (k < 2016) {              // local_v
      const int s = k - 1728, h = s / 24, rem = s % 24, p = rem / 3, x = rem % 3;
      const float* av = scav + ((size_t)h * NN + i) * 40 + 16 + p * 3;
      const float a0 = av[0] - tl[r][0], a1 = av[1] - tl[r][1], a2 = av[2] - tl[r][2];
      val = rinv[r][x * 3 + 0] * a0 + rinv[r][x * 3 + 1] * a1 + rinv[r][x * 3 + 2] * a2;
    } else {                            // v_len
      const int s = k - 2016, h = s >> 3, p = s & 7;
      const float* av = scav + ((size_t)h * NN + i) * 40 + 16 + p * 3;
      const float a0 = av[0] - tl[r][0], a1 = av[1] - tl[r][1], a2 = av[2] - tl[r][2];
      const float l0 = rinv[r][0] * a0 + rinv[r][1] * a1 + rinv[r][2] * a2;
      const float l1 = rinv[r][3] * a0 + rinv[r][4] * a1 + rinv[r][5] * a2;
      const float l2 = rinv[r][6] * a0 + rinv[r][7] * a1 + rinv[r][8] * a2;
      val = sqrtf(l0 * l0 + l1 * l1 + l2 * l2);
    }
    comb[r][k] = val;
  }
  __syncthreads();
  for (int c = tid; c < 384; c += 256) {
    float acc0 = bfin[c] + node[(size_t)(i0 + 0) * 384 + c];
    float acc1 = bfin[c] + node[(size_t)(i0 + 1) * 384 + c];
    float acc2 = bfin[c] + node[(size_t)(i0 + 2) * 384 + c];
    float acc3 = bfin[c] + node[(size_t)(i0 + 3) * 384 + c];
    for (int k4 = 0; k4 < 528; ++k4) {
      const int k = k4 * 4;
      const float w0 = Wfin[(size_t)(k + 0) * 384 + c];
      const float w1 = Wfin[(size_t)(k + 1) * 384 + c];
      const float w2 = Wfin[(size_t)(k + 2) * 384 + c];
      const float w3 = Wfin[(size_t)(k + 3) * 384 + c];
      const float4 c0v = *(const float4*)&comb[0][k];
      const float4 c1v = *(const float4*)&comb[1][k];
      const float4 c2v = *(const float4*)&comb[2][k];
      const float4 c3v = *(const float4*)&comb[3][k];
      acc0 += c0v.x * w0 + c0v.y * w1 + c0v.z * w2 + c0v.w * w3;
      acc1 += c1v.x * w0 + c1v.y * w1 + c1v.z * w2 + c1v.w * w3;
      acc2 += c2v.x * w0 + c2v.y * w1 + c2v.z * w2 + c2v.w * w3;
      acc3 += c3v.x * w0 + c3v.y * w1 + c3v.z * w2 + c3v.w * w3;
    }
    out[(size_t)(i0 + 0) * 384 + c] = acc0;
    out[(size_t)(i0 + 1) * 384 + c] = acc1;
    out[(size_t)(i0 + 2) * 384 + c] = acc2;
    out[(size_t)(i0 + 3) * 384 + c] = acc3;
  }
}

}  // namespace

extern "C" void kernel_launch(void* const* d_in, const int* in_sizes, int n_in,
                              void* d_out, int out_size, void* d_ws, size_t ws_size,
                              hipStream_t stream) {
  const float* node   = (const float*)d_in[0];
  const float* edge   = (const float*)d_in[1];
  const float* R      = (const float*)d_in[2];
  const float* t      = (const float*)d_in[3];
  const float* Wqkv   = (const float*)d_in[4];
  const float* Wvqk   = (const float*)d_in[5];
  const float* Wvv    = (const float*)d_in[6];
  const float* Webias = (const float*)d_in[7];
  const float* Wfin   = (const float*)d_in[8];
  const float* bfin   = (const float*)d_in[9];
  float* out = (float*)d_out;

  float* ws = (float*)d_ws;
  float* proj   = ws;                    // 768*1152      = 884736
  float* sq     = proj   + 884736;       // 12*768*16     = 147456
  float* sk     = sq     + 147456;       // 147456
  float* gk     = sk     + 147456;       // 12*768*12     = 110592
  float* gq     = gk     + 110592;       // 110592
  float* ksq    = gq     + 110592;       // 12*768        = 9216
  float* qsq    = ksq    + 9216;         // 9216
  float* wbT    = qsq    + 9216;         // 12*128        = 1536
  float* V      = wbT    + 1536;         // 12*768*40     = 368640
  float* logits = V      + 368640;       // 12*768*768    = 7077888 (later attn)
  float* eout   = logits + 7077888;      // 768*1536      = 1179648
  float* scav   = eout   + 1179648;      // 12*768*40     = 368640
  // total ~10.42M floats = ~41.7 MB

  hipLaunchKernelGGL(k_proj, dim3(96), dim3(384), 0, stream,
                     node, Wqkv, Wvqk, Wvv, proj);
  hipLaunchKernelGGL(k_geom, dim3(36), dim3(256), 0, stream,
                     proj, R, t, Webias, sq, sk, gk, gq, ksq, qsq, wbT, V);
  hipLaunchKernelGGL(k_logits, dim3(12, 768), dim3(256), 0, stream,
                     edge, wbT, sq, sk, gk, gq, ksq, qsq, logits);
  hipLaunchKernelGGL(k_softmax, dim3(12 * 768), dim3(256), 0, stream, logits);
  hipLaunchKernelGGL(k_eout, dim3(768), dim3(192), 0, stream,
                     edge, logits, eout);
  hipLaunchKernelGGL(k_scav, dim3(12, 12), dim3(320), 0, stream,
                     logits, V, scav);
  hipLaunchKernelGGL(k_final, dim3(192), dim3(256), 0, stream,
                     node, R, t, eout, scav, Wfin, bfin, out);
}

// Round 2
// 569.248 us; speedup vs baseline: 1.3358x; 1.3358x over previous
//
#include <hip/hip_runtime.h>
#include <cmath>

// InvariantPointAttention, N=768, H=12, D=16, NQP=4, NVP=8, NODE=384, EDGE=128.
// fp32. Flash-style fused attention: edge (302 MB) streamed exactly once.

namespace {

constexpr int NN = 768;
constexpr int NH = 12;

constexpr float S3 = 0.5773502691896258f;        // 3^-0.5
constexpr float C1 = 0.25f * S3;                 // (1/sqrt(16))/sqrt(3)
constexpr float C2 = 0.23570226039551584f * S3;  // 2*wc/sqrt(3)
constexpr float C3 = 0.11785113019775792f * S3;  // wc/sqrt(3)

#define LGKM0 asm volatile("s_waitcnt lgkmcnt(0)" ::: "memory")
#define SCHED0 __builtin_amdgcn_sched_barrier(0)
#define BARRIER __builtin_amdgcn_s_barrier()

// ---------------------------------------------------------------- k_proj ----
// proj[768][1152] = node[768][384] @ [Wqkv(576) | Wvqk(288) | Wvv(288)]
// 192 blocks x 288 thr; 4 rows/block; thread owns 4 consecutive cols (float4).
__global__ __launch_bounds__(288) void k_proj(const float* __restrict__ node,
    const float* __restrict__ Wqkv, const float* __restrict__ Wvqk,
    const float* __restrict__ Wvv, float* __restrict__ proj) {
  __shared__ __align__(16) float nl[4][384];
  const int i0 = blockIdx.x * 4;
  const int tid = threadIdx.x;
  for (int idx = tid; idx < 4 * 384; idx += 288)
    ((float*)nl)[idx] = node[(size_t)i0 * 384 + idx];
  __syncthreads();
  const int c0 = tid * 4;
  const float* W; int ld, col;
  if (c0 < 576)      { W = Wqkv; ld = 576; col = c0; }
  else if (c0 < 864) { W = Wvqk; ld = 288; col = c0 - 576; }
  else               { W = Wvv;  ld = 288; col = c0 - 864; }
  float4 acc[4];
#pragma unroll
  for (int r = 0; r < 4; ++r) acc[r] = make_float4(0.f, 0.f, 0.f, 0.f);
#pragma unroll 4
  for (int k = 0; k < 384; ++k) {
    const float4 w4 = *(const float4*)&W[(size_t)k * ld + col];
#pragma unroll
    for (int r = 0; r < 4; ++r) {
      const float nv = nl[r][k];
      acc[r].x += nv * w4.x; acc[r].y += nv * w4.y;
      acc[r].z += nv * w4.z; acc[r].w += nv * w4.w;
    }
  }
#pragma unroll
  for (int r = 0; r < 4; ++r)
    *(float4*)&proj[(size_t)(i0 + r) * 1152 + c0] = acc[r];
}

// ---------------------------------------------------------------- k_geom ----
__global__ __launch_bounds__(256) void k_geom(const float* __restrict__ proj,
    const float* __restrict__ R, const float* __restrict__ t,
    const float* __restrict__ Webias,
    float* __restrict__ sq, float* __restrict__ sk,
    float* __restrict__ gk, float* __restrict__ gq,
    float* __restrict__ ksq, float* __restrict__ qsq,
    float* __restrict__ wbT, float* __restrict__ V) {
  const int gid = blockIdx.x * 256 + threadIdx.x;
  if (gid < 128 * 12) {
    const int d = gid / 12, h = gid % 12;
    wbT[h * 128 + d] = Webias[gid];
  }
  if (gid >= NN * NH) return;
  const int n = gid / NH, h = gid % NH;
  const float* pr = proj + (size_t)n * 1152;
  const float* Rn = R + n * 9;
  const float t0 = t[n * 3 + 0], t1 = t[n * 3 + 1], t2 = t[n * 3 + 2];
  const size_t hn = (size_t)h * NN + n;
#pragma unroll
  for (int d = 0; d < 16; ++d) {
    sq[hn * 16 + d] = pr[h * 16 + d];
    sk[hn * 16 + d] = pr[(12 + h) * 16 + d];
    V[hn * 40 + d]  = pr[(24 + h) * 16 + d];
  }
  float qs = 0.f, ks = 0.f;
#pragma unroll
  for (int p = 0; p < 4; ++p) {
    {
      const float vx = pr[576 + (h * 4 + p) * 3 + 0];
      const float vy = pr[576 + (h * 4 + p) * 3 + 1];
      const float vz = pr[576 + (h * 4 + p) * 3 + 2];
      const float g0 = Rn[0] * vx + Rn[1] * vy + Rn[2] * vz + t0;
      const float g1 = Rn[3] * vx + Rn[4] * vy + Rn[5] * vz + t1;
      const float g2 = Rn[6] * vx + Rn[7] * vy + Rn[8] * vz + t2;
      gq[hn * 12 + p * 3 + 0] = g0; gq[hn * 12 + p * 3 + 1] = g1;
      gq[hn * 12 + p * 3 + 2] = g2;
      qs += g0 * g0 + g1 * g1 + g2 * g2;
    }
    {
      const float vx = pr[576 + ((12 + h) * 4 + p) * 3 + 0];
      const float vy = pr[576 + ((12 + h) * 4 + p) * 3 + 1];
      const float vz = pr[576 + ((12 + h) * 4 + p) * 3 + 2];
      const float g0 = Rn[0] * vx + Rn[1] * vy + Rn[2] * vz + t0;
      const float g1 = Rn[3] * vx + Rn[4] * vy + Rn[5] * vz + t1;
      const float g2 = Rn[6] * vx + Rn[7] * vy + Rn[8] * vz + t2;
      gk[hn * 12 + p * 3 + 0] = g0; gk[hn * 12 + p * 3 + 1] = g1;
      gk[hn * 12 + p * 3 + 2] = g2;
      ks += g0 * g0 + g1 * g1 + g2 * g2;
    }
  }
  qsq[hn] = qs;
  ksq[hn] = ks;
#pragma unroll
  for (int p = 0; p < 8; ++p) {
    const float vx = pr[864 + (h * 8 + p) * 3 + 0];
    const float vy = pr[864 + (h * 8 + p) * 3 + 1];
    const float vz = pr[864 + (h * 8 + p) * 3 + 2];
    V[hn * 40 + 16 + p * 3 + 0] = Rn[0] * vx + Rn[1] * vy + Rn[2] * vz + t0;
    V[hn * 40 + 16 + p * 3 + 1] = Rn[3] * vx + Rn[4] * vy + Rn[5] * vz + t1;
    V[hn * 40 + 16 + p * 3 + 2] = Rn[6] * vx + Rn[7] * vy + Rn[8] * vz + t2;
  }
}

// --------------------------------------------------------------- k_fused ----
// One block per i. Streams edge[i,:,:] once in 12 tiles of 64 rows.
// Per tile: coalesced global->reg->LDS (XOR-swizzled 16B blocks), edge_bias +
// logits (wave w owns heads 3w..3w+2, lane = jj), online softmax, online
// edge_out accumulation (lane owns d-pair 2*lane). Raw logits + m, 1/l -> glob.
__global__ __launch_bounds__(256) void k_fused(
    const float* __restrict__ edge, const float* __restrict__ wbT,
    const float* __restrict__ sq, const float* __restrict__ sk,
    const float* __restrict__ gk, const float* __restrict__ gq,
    const float* __restrict__ ksq, const float* __restrict__ qsq,
    float* __restrict__ logits, float* __restrict__ eout,
    float* __restrict__ msm, float* __restrict__ linv) {
  __shared__ __align__(16) float et[64 * 128];   // swizzled: 32 KB
  __shared__ __align__(16) float p_sh[12][64];   // 3 KB
  const int i = blockIdx.x;
  const int tid = threadIdx.x;
  const int lane = tid & 63;
  const int wg = __builtin_amdgcn_readfirstlane(tid >> 6);  // 0..3
  const int h0 = wg * 3;
  const int jj7 = lane & 7;

  float mrun[3] = {-3.0e38f, -3.0e38f, -3.0e38f};
  float lrun[3] = {0.f, 0.f, 0.f};
  float Oa[3][2] = {{0.f, 0.f}, {0.f, 0.f}, {0.f, 0.f}};
  const int d0 = lane * 2;

  // prologue: tile 0 -> regs
  float4 ra[8];
#pragma unroll
  for (int q = 0; q < 8; ++q) {
    const int idx16 = tid + q * 256;
    const int jj = idx16 >> 5, k8 = idx16 & 31;
    ra[q] = *(const float4*)&edge[((size_t)(i * NN + jj)) * 128 + k8 * 4];
  }

  for (int t = 0; t < 12; ++t) {
    const int j0 = t * 64;
    SCHED0; BARRIER; SCHED0;   // previous tile's consumers done
    // regs -> LDS (swizzled: 16B block k8 of row jj lands at k8 ^ (jj&7))
#pragma unroll
    for (int q = 0; q < 8; ++q) {
      const int idx16 = tid + q * 256;
      const int jj = idx16 >> 5, k8 = idx16 & 31;
      *(float4*)&et[(((jj << 5) + (k8 ^ (jj & 7))) << 2)] = ra[q];
    }
    // prefetch next tile into regs (flies during compute)
    if (t < 11) {
#pragma unroll
      for (int q = 0; q < 8; ++q) {
        const int idx16 = tid + q * 256;
        const int jj = idx16 >> 5, k8 = idx16 & 31;
        ra[q] = *(const float4*)&edge[((size_t)(i * NN + j0 + 64 + jj)) * 128 + k8 * 4];
      }
    }
    LGKM0; SCHED0; BARRIER; SCHED0;  // all waves' ds_writes visible

    // ---- edge bias for (row jj = lane, heads h0..h0+2)
    const int j = j0 + lane;
    float eb[3] = {0.f, 0.f, 0.f};
#pragma unroll 8
    for (int k8 = 0; k8 < 32; ++k8) {
      const float4 e4 = *(const float4*)&et[((lane << 5) + (k8 ^ jj7)) << 2];
      const float4 wa = *(const float4*)&wbT[(h0 + 0) * 128 + k8 * 4];
      const float4 wb = *(const float4*)&wbT[(h0 + 1) * 128 + k8 * 4];
      const float4 wc = *(const float4*)&wbT[(h0 + 2) * 128 + k8 * 4];
      eb[0] += e4.x * wa.x + e4.y * wa.y + e4.z * wa.z + e4.w * wa.w;
      eb[1] += e4.x * wb.x + e4.y * wb.y + e4.z * wb.z + e4.w * wb.w;
      eb[2] += e4.x * wc.x + e4.y * wc.y + e4.z * wc.z + e4.w * wc.w;
    }

    // ---- full logits
    float lg[3];
#pragma unroll
    for (int u = 0; u < 3; ++u) {
      const int h = h0 + u;
      const float* sqp = sq + ((size_t)h * NN + i) * 16;   // uniform -> s_load
      const float* skp = sk + ((size_t)h * NN + j) * 16;
      float dsk = 0.f;
#pragma unroll
      for (int k4 = 0; k4 < 4; ++k4) {
        const float4 a = *(const float4*)(sqp + k4 * 4);
        const float4 b = *(const float4*)(skp + k4 * 4);
        dsk += a.x * b.x + a.y * b.y + a.z * b.z + a.w * b.w;
      }
      const float* gkp = gk + ((size_t)h * NN + i) * 12;   // uniform
      const float* gqp = gq + ((size_t)h * NN + j) * 12;
      float dgq = 0.f;
#pragma unroll
      for (int k4 = 0; k4 < 3; ++k4) {
        const float4 a = *(const float4*)(gkp + k4 * 4);
        const float4 b = *(const float4*)(gqp + k4 * 4);
        dgq += a.x * b.x + a.y * b.y + a.z * b.z + a.w * b.w;
      }
      lg[u] = C1 * dsk + C2 * dgq
            - C3 * (ksq[(size_t)h * NN + i] + qsq[(size_t)h * NN + j])
            + S3 * eb[u];
      logits[((size_t)h * NN + i) * NN + j] = lg[u];
    }

    // ---- online softmax update (per-wave state, wave-uniform after reduce)
#pragma unroll
    for (int u = 0; u < 3; ++u) {
      float tm = lg[u];
#pragma unroll
      for (int off = 32; off; off >>= 1) tm = fmaxf(tm, __shfl_xor(tm, off, 64));
      const float mn = fmaxf(mrun[u], tm);
      const float f = __expf(mrun[u] - mn);
      const float p = __expf(lg[u] - mn);
      float sp = p;
#pragma unroll
      for (int off = 32; off; off >>= 1) sp += __shfl_xor(sp, off, 64);
      lrun[u] = lrun[u] * f + sp;
      mrun[u] = mn;
      Oa[u][0] *= f; Oa[u][1] *= f;
      p_sh[h0 + u][lane] = p;
    }
    LGKM0; SCHED0;   // wave-local p_sh writes complete (only own wave reads)

    // ---- online edge_out accumulation: lane owns (d0, d0+1) for 3 heads
#pragma unroll 2
    for (int jb = 0; jb < 16; ++jb) {
      const float4 pa = *(const float4*)&p_sh[h0 + 0][jb * 4];
      const float4 pb = *(const float4*)&p_sh[h0 + 1][jb * 4];
      const float4 pc = *(const float4*)&p_sh[h0 + 2][jb * 4];
#pragma unroll
      for (int q = 0; q < 4; ++q) {
        const int jj = jb * 4 + q;
        const float2 e2 = *(const float2*)&et[(jj << 7) + (((lane >> 1) ^ (jj & 7)) << 2) + ((lane & 1) << 1)];
        const float pav = q == 0 ? pa.x : q == 1 ? pa.y : q == 2 ? pa.z : pa.w;
        const float pbv = q == 0 ? pb.x : q == 1 ? pb.y : q == 2 ? pb.z : pb.w;
        const float pcv = q == 0 ? pc.x : q == 1 ? pc.y : q == 2 ? pc.z : pc.w;
        Oa[0][0] += pav * e2.x; Oa[0][1] += pav * e2.y;
        Oa[1][0] += pbv * e2.x; Oa[1][1] += pbv * e2.y;
        Oa[2][0] += pcv * e2.x; Oa[2][1] += pcv * e2.y;
      }
    }
  }

  // ---- epilogue
  float* ep = eout + (size_t)i * 1536;
#pragma unroll
  for (int u = 0; u < 3; ++u) {
    const float il = 1.0f / lrun[u];
    *(float2*)&ep[(h0 + u) * 128 + d0] = make_float2(Oa[u][0] * il, Oa[u][1] * il);
  }
  if (lane == 0) {
#pragma unroll
    for (int u = 0; u < 3; ++u) {
      msm[(size_t)(h0 + u) * NN + i] = mrun[u];
      linv[(size_t)(h0 + u) * NN + i] = 1.0f / lrun[u];
    }
  }
}

// ---------------------------------------------------------------- k_scav ----
// scav[h][i][0..39] = sum_j attn[h,i,j] * V[h][j][0..39], attn rebuilt from
// raw logits: attn = exp(lg - m[h,i]) * linv[h,i].
__global__ __launch_bounds__(320) void k_scav(const float* __restrict__ logits,
    const float* __restrict__ msm, const float* __restrict__ linv,
    const float* __restrict__ V, float* __restrict__ scav) {
  const int i0 = blockIdx.x * 64;
  const int h  = blockIdx.y;
  const int tid = threadIdx.x;
  const int r0 = (tid / 20) * 4;
  const int c0 = (tid % 20) * 2;
  __shared__ __align__(16) float At[64][68];  // [jj][r]
  float acc[4][2] = {{0.f,0.f},{0.f,0.f},{0.f,0.f},{0.f,0.f}};
  for (int jt = 0; jt < 12; ++jt) {
    const int j0 = jt * 64;
    __syncthreads();
    for (int idx = tid; idx < 64 * 64; idx += 320) {
      const int r = idx / 64, jj = idx % 64;
      const float lg = logits[((size_t)h * NN + i0 + r) * NN + j0 + jj];
      At[jj][r] = __expf(lg - msm[(size_t)h * NN + i0 + r]) * linv[(size_t)h * NN + i0 + r];
    }
    __syncthreads();
    for (int jj = 0; jj < 64; ++jj) {
      const float4 a4 = *(const float4*)&At[jj][r0];
      const float2 b2 = *(const float2*)(V + ((size_t)h * NN + j0 + jj) * 40 + c0);
      acc[0][0] += a4.x * b2.x; acc[0][1] += a4.x * b2.y;
      acc[1][0] += a4.y * b2.x; acc[1][1] += a4.y * b2.y;
      acc[2][0] += a4.z * b2.x; acc[2][1] += a4.z * b2.y;
      acc[3][0] += a4.w * b2.x; acc[3][1] += a4.w * b2.y;
    }
  }
#pragma unroll
  for (int u = 0; u < 4; ++u)
#pragma unroll
    for (int v = 0; v < 2; ++v)
      scav[((size_t)h * NN + i0 + r0 + u) * 40 + c0 + v] = acc[u][v];
}

// --------------------------------------------------------------- k_final ----
__global__ __launch_bounds__(256) void k_final(const float* __restrict__ node,
    const float* __restrict__ R, const float* __restrict__ t,
    const float* __restrict__ eout, const float* __restrict__ scav,
    const float* __restrict__ Wfin, const float* __restrict__ bfin,
    float* __restrict__ out) {
  const int i0 = blockIdx.x * 4;
  const int tid = threadIdx.x;
  __shared__ __align__(16) float comb[4][2112];
  __shared__ float rinv[4][9];
  __shared__ float tl[4][3];
  if (tid < 4) {
    const int i = i0 + tid;
    const float* Rn = R + i * 9;
    const float r00 = Rn[0], r01 = Rn[1], r02 = Rn[2];
    const float r10 = Rn[3], r11 = Rn[4], r12 = Rn[5];
    const float r20 = Rn[6], r21 = Rn[7], r22 = Rn[8];
    const float det = r00 * (r11 * r22 - r12 * r21)
                    - r01 * (r10 * r22 - r12 * r20)
                    + r02 * (r10 * r21 - r11 * r20);
    const float id = 1.0f / det;
    rinv[tid][0] = (r11 * r22 - r12 * r21) * id;
    rinv[tid][1] = (r02 * r21 - r01 * r22) * id;
    rinv[tid][2] = (r01 * r12 - r02 * r11) * id;
    rinv[tid][3] = (r12 * r20 - r10 * r22) * id;
    rinv[tid][4] = (r00 * r22 - r02 * r20) * id;
    rinv[tid][5] = (r02 * r10 - r00 * r12) * id;
    rinv[tid][6] = (r10 * r21 - r11 * r20) * id;
    rinv[tid][7] = (r01 * r20 - r00 * r21) * id;
    rinv[tid][8] = (r00 * r11 - r01 * r10) * id;
    tl[tid][0] = t[i * 3 + 0]; tl[tid][1] = t[i * 3 + 1]; tl[tid][2] = t[i * 3 + 2];
  }
  __syncthreads();
  for (int idx = tid; idx < 4 * 2112; idx += 256) {
    const int r = idx / 2112, k = idx % 2112;
    const int i = i0 + r;
    float val;
    if (k < 1536) {
      val = eout[(size_t)i * 1536 + k];
    } else if (k < 1728) {
      const int s = k - 1536, h = s >> 4, d = s & 15;
      val = scav[((size_t)h * NN + i) * 40 + d];
    } else if (k < 2016) {
      const int s = k - 1728, h = s / 24, rem = s % 24, p = rem / 3, x = rem % 3;
      const float* av = scav + ((size_t)h * NN + i) * 40 + 16 + p * 3;
      const float a0 = av[0] - tl[r][0], a1 = av[1] - tl[r][1], a2 = av[2] - tl[r][2];
      val = rinv[r][x * 3 + 0] * a0 + rinv[r][x * 3 + 1] * a1 + rinv[r][x * 3 + 2] * a2;
    } else {
      const int s = k - 2016, h = s >> 3, p = s & 7;
      const float* av = scav + ((size_t)h * NN + i) * 40 + 16 + p * 3;
      const float a0 = av[0] - tl[r][0], a1 = av[1] - tl[r][1], a2 = av[2] - tl[r][2];
      const float l0 = rinv[r][0] * a0 + rinv[r][1] * a1 + rinv[r][2] * a2;
      const float l1 = rinv[r][3] * a0 + rinv[r][4] * a1 + rinv[r][5] * a2;
      const float l2 = rinv[r][6] * a0 + rinv[r][7] * a1 + rinv[r][8] * a2;
      val = sqrtf(l0 * l0 + l1 * l1 + l2 * l2);
    }
    comb[r][k] = val;
  }
  __syncthreads();
  for (int c = tid; c < 384; c += 256) {
    float acc0 = bfin[c] + node[(size_t)(i0 + 0) * 384 + c];
    float acc1 = bfin[c] + node[(size_t)(i0 + 1) * 384 + c];
    float acc2 = bfin[c] + node[(size_t)(i0 + 2) * 384 + c];
    float acc3 = bfin[c] + node[(size_t)(i0 + 3) * 384 + c];
    for (int k4 = 0; k4 < 528; ++k4) {
      const int k = k4 * 4;
      const float w0 = Wfin[(size_t)(k + 0) * 384 + c];
      const float w1 = Wfin[(size_t)(k + 1) * 384 + c];
      const float w2 = Wfin[(size_t)(k + 2) * 384 + c];
      const float w3 = Wfin[(size_t)(k + 3) * 384 + c];
      const float4 c0v = *(const float4*)&comb[0][k];
      const float4 c1v = *(const float4*)&comb[1][k];
      const float4 c2v = *(const float4*)&comb[2][k];
      const float4 c3v = *(const float4*)&comb[3][k];
      acc0 += c0v.x * w0 + c0v.y * w1 + c0v.z * w2 + c0v.w * w3;
      acc1 += c1v.x * w0 + c1v.y * w1 + c1v.z * w2 + c1v.w * w3;
      acc2 += c2v.x * w0 + c2v.y * w1 + c2v.z * w2 + c2v.w * w3;
      acc3 += c3v.x * w0 + c3v.y * w1 + c3v.z * w2 + c3v.w * w3;
    }
    out[(size_t)(i0 + 0) * 384 + c] = acc0;
    out[(size_t)(i0 + 1) * 384 + c] = acc1;
    out[(size_t)(i0 + 2) * 384 + c] = acc2;
    out[(size_t)(i0 + 3) * 384 + c] = acc3;
  }
}

}  // namespace

extern "C" void kernel_launch(void* const* d_in, const int* in_sizes, int n_in,
                              void* d_out, int out_size, void* d_ws, size_t ws_size,
                              hipStream_t stream) {
  const float* node   = (const float*)d_in[0];
  const float* edge   = (const float*)d_in[1];
  const float* R      = (const float*)d_in[2];
  const float* t      = (const float*)d_in[3];
  const float* Wqkv   = (const float*)d_in[4];
  const float* Wvqk   = (const float*)d_in[5];
  const float* Wvv    = (const float*)d_in[6];
  const float* Webias = (const float*)d_in[7];
  const float* Wfin   = (const float*)d_in[8];
  const float* bfin   = (const float*)d_in[9];
  float* out = (float*)d_out;

  float* ws = (float*)d_ws;
  float* proj   = ws;                    // 884736
  float* sq     = proj   + 884736;       // 147456
  float* sk     = sq     + 147456;       // 147456
  float* gk     = sk     + 147456;       // 110592
  float* gq     = gk     + 110592;       // 110592
  float* ksq    = gq     + 110592;       // 9216
  float* qsq    = ksq    + 9216;         // 9216
  float* wbT    = qsq    + 9216;         // 1536
  float* V      = wbT    + 1536;         // 368640
  float* logits = V      + 368640;       // 7077888 (raw logits)
  float* eout   = logits + 7077888;      // 1179648
  float* scav   = eout   + 1179648;      // 368640
  float* msm    = scav   + 368640;       // 9216
  float* linv   = msm    + 9216;         // 9216
  // total ~10.45M floats = ~41.8 MB

  hipLaunchKernelGGL(k_proj, dim3(192), dim3(288), 0, stream,
                     node, Wqkv, Wvqk, Wvv, proj);
  hipLaunchKernelGGL(k_geom, dim3(36), dim3(256), 0, stream,
                     proj, R, t, Webias, sq, sk, gk, gq, ksq, qsq, wbT, V);
  hipLaunchKernelGGL(k_fused, dim3(768), dim3(256), 0, stream,
                     edge, wbT, sq, sk, gk, gq, ksq, qsq, logits, eout, msm, linv);
  hipLaunchKernelGGL(k_scav, dim3(12, 12), dim3(320), 0, stream,
                     logits, msm, linv, V, scav);
  hipLaunchKernelGGL(k_final, dim3(192), dim3(256), 0, stream,
                     node, R, t, eout, scav, Wfin, bfin, out);
}

// Round 3
// 457.348 us; speedup vs baseline: 1.6626x; 1.2447x over previous
//
#include <hip/hip_runtime.h>
#include <cmath>

// InvariantPointAttention, N=768, H=12, D=16, NQP=4, NVP=8, NODE=384, EDGE=128.
// fp32. Flash-fused attention with global_load_lds double-buffer (counted
// vmcnt), source-swizzled LDS, defer-max online softmax.

namespace {

constexpr int NN = 768;
constexpr int NH = 12;

constexpr float S3 = 0.5773502691896258f;        // 3^-0.5
constexpr float C1 = 0.25f * S3;                 // (1/sqrt(16))/sqrt(3)
constexpr float C2 = 0.23570226039551584f * S3;  // 2*wc/sqrt(3)
constexpr float C3 = 0.11785113019775792f * S3;  // wc/sqrt(3)

#define LGKM0 asm volatile("s_waitcnt lgkmcnt(0)" ::: "memory")
#define SCHED0 __builtin_amdgcn_sched_barrier(0)
#define BARRIER __builtin_amdgcn_s_barrier()

// ---------------------------------------------------------------- k_proj ----
__global__ __launch_bounds__(288) void k_proj(const float* __restrict__ node,
    const float* __restrict__ Wqkv, const float* __restrict__ Wvqk,
    const float* __restrict__ Wvv, float* __restrict__ proj) {
  __shared__ __align__(16) float nl[4][384];
  const int i0 = blockIdx.x * 4;
  const int tid = threadIdx.x;
  for (int idx = tid; idx < 4 * 384; idx += 288)
    ((float*)nl)[idx] = node[(size_t)i0 * 384 + idx];
  __syncthreads();
  const int c0 = tid * 4;
  const float* W; int ld, col;
  if (c0 < 576)      { W = Wqkv; ld = 576; col = c0; }
  else if (c0 < 864) { W = Wvqk; ld = 288; col = c0 - 576; }
  else               { W = Wvv;  ld = 288; col = c0 - 864; }
  float4 acc[4];
#pragma unroll
  for (int r = 0; r < 4; ++r) acc[r] = make_float4(0.f, 0.f, 0.f, 0.f);
#pragma unroll 4
  for (int k = 0; k < 384; ++k) {
    const float4 w4 = *(const float4*)&W[(size_t)k * ld + col];
#pragma unroll
    for (int r = 0; r < 4; ++r) {
      const float nv = nl[r][k];
      acc[r].x += nv * w4.x; acc[r].y += nv * w4.y;
      acc[r].z += nv * w4.z; acc[r].w += nv * w4.w;
    }
  }
#pragma unroll
  for (int r = 0; r < 4; ++r)
    *(float4*)&proj[(size_t)(i0 + r) * 1152 + c0] = acc[r];
}

// ---------------------------------------------------------------- k_geom ----
__global__ __launch_bounds__(256) void k_geom(const float* __restrict__ proj,
    const float* __restrict__ R, const float* __restrict__ t,
    const float* __restrict__ Webias,
    float* __restrict__ sq, float* __restrict__ sk,
    float* __restrict__ gk, float* __restrict__ gq,
    float* __restrict__ ksq, float* __restrict__ qsq,
    float* __restrict__ wbT, float* __restrict__ V) {
  const int gid = blockIdx.x * 256 + threadIdx.x;
  if (gid < 128 * 12) {
    const int d = gid / 12, h = gid % 12;
    wbT[h * 128 + d] = Webias[gid];
  }
  if (gid >= NN * NH) return;
  const int n = gid / NH, h = gid % NH;
  const float* pr = proj + (size_t)n * 1152;
  const float* Rn = R + n * 9;
  const float t0 = t[n * 3 + 0], t1 = t[n * 3 + 1], t2 = t[n * 3 + 2];
  const size_t hn = (size_t)h * NN + n;
#pragma unroll
  for (int d = 0; d < 16; ++d) {
    sq[hn * 16 + d] = pr[h * 16 + d];
    sk[hn * 16 + d] = pr[(12 + h) * 16 + d];
    V[hn * 40 + d]  = pr[(24 + h) * 16 + d];
  }
  float qs = 0.f, ks = 0.f;
#pragma unroll
  for (int p = 0; p < 4; ++p) {
    {
      const float vx = pr[576 + (h * 4 + p) * 3 + 0];
      const float vy = pr[576 + (h * 4 + p) * 3 + 1];
      const float vz = pr[576 + (h * 4 + p) * 3 + 2];
      const float g0 = Rn[0] * vx + Rn[1] * vy + Rn[2] * vz + t0;
      const float g1 = Rn[3] * vx + Rn[4] * vy + Rn[5] * vz + t1;
      const float g2 = Rn[6] * vx + Rn[7] * vy + Rn[8] * vz + t2;
      gq[hn * 12 + p * 3 + 0] = g0; gq[hn * 12 + p * 3 + 1] = g1;
      gq[hn * 12 + p * 3 + 2] = g2;
      qs += g0 * g0 + g1 * g1 + g2 * g2;
    }
    {
      const float vx = pr[576 + ((12 + h) * 4 + p) * 3 + 0];
      const float vy = pr[576 + ((12 + h) * 4 + p) * 3 + 1];
      const float vz = pr[576 + ((12 + h) * 4 + p) * 3 + 2];
      const float g0 = Rn[0] * vx + Rn[1] * vy + Rn[2] * vz + t0;
      const float g1 = Rn[3] * vx + Rn[4] * vy + Rn[5] * vz + t1;
      const float g2 = Rn[6] * vx + Rn[7] * vy + Rn[8] * vz + t2;
      gk[hn * 12 + p * 3 + 0] = g0; gk[hn * 12 + p * 3 + 1] = g1;
      gk[hn * 12 + p * 3 + 2] = g2;
      ks += g0 * g0 + g1 * g1 + g2 * g2;
    }
  }
  qsq[hn] = qs;
  ksq[hn] = ks;
#pragma unroll
  for (int p = 0; p < 8; ++p) {
    const float vx = pr[864 + (h * 8 + p) * 3 + 0];
    const float vy = pr[864 + (h * 8 + p) * 3 + 1];
    const float vz = pr[864 + (h * 8 + p) * 3 + 2];
    V[hn * 40 + 16 + p * 3 + 0] = Rn[0] * vx + Rn[1] * vy + Rn[2] * vz + t0;
    V[hn * 40 + 16 + p * 3 + 1] = Rn[3] * vx + Rn[4] * vy + Rn[5] * vz + t1;
    V[hn * 40 + 16 + p * 3 + 2] = Rn[6] * vx + Rn[7] * vy + Rn[8] * vz + t2;
  }
}

// --------------------------------------------------------------- k_fused ----
// One block per i. edge[i,:,:] streamed once, 12 tiles of 64 rows, via
// global_load_lds into linear LDS with SOURCE-swizzled addresses:
// LDS slot (row, blkP) holds global 16B-block blkP ^ (row&7).
// Wave w owns heads 3w..3w+2 and loads rows 16w..16w+15 (8 instrs).
// Defer-max online softmax; PV: lane = (parity=lane>>5, dquad=lane&31).
__global__ __launch_bounds__(256, 2) void k_fused(
    const float* __restrict__ edge, const float* __restrict__ wbT,
    const float* __restrict__ sq, const float* __restrict__ sk,
    const float* __restrict__ gk, const float* __restrict__ gq,
    const float* __restrict__ ksq, const float* __restrict__ qsq,
    float* __restrict__ logits, float* __restrict__ eout,
    float* __restrict__ msm, float* __restrict__ linv) {
  __shared__ __align__(16) float et[2][64 * 128];   // 64 KB dbuf
  __shared__ __align__(16) float p_sh[12][2][32];   // [h][parity][s] 3 KB
  const int i = blockIdx.x;
  const int tid = threadIdx.x;
  const int lane = tid & 63;
  const int w = __builtin_amdgcn_readfirstlane(tid >> 6);
  const int h0 = w * 3;
  const int half = lane >> 5;
  const int dq = lane & 31;
  const int rx = lane & 7;

#define ISSUE_TILE(jb, bufidx) do {                                          \
    _Pragma("unroll")                                                        \
    for (int q = 0; q < 8; ++q) {                                            \
      const int rl = ((w * 8 + q) << 1) | half;                              \
      const int blk = (lane & 31) ^ (rl & 7);                                \
      const float* gp = edge + ((size_t)i * NN + (jb) + rl) * 128 + (blk << 2); \
      float* lp = &et[bufidx][(w * 8 + q) * 256];                            \
      __builtin_amdgcn_global_load_lds(                                      \
          (const __attribute__((address_space(1))) void*)gp,                 \
          (__attribute__((address_space(3))) void*)lp, 16, 0, 0);            \
    }                                                                        \
  } while (0)

  float mrun[3] = {-3.0e38f, -3.0e38f, -3.0e38f};
  float lsum[3] = {0.f, 0.f, 0.f};
  float4 Oa[3];
#pragma unroll
  for (int u = 0; u < 3; ++u) Oa[u] = make_float4(0.f, 0.f, 0.f, 0.f);

  // prologue: tile 0
  ISSUE_TILE(0, 0);

  for (int t = 0; t < 12; ++t) {
    const int cur = t & 1;
    SCHED0; BARRIER; SCHED0;      // entry: everyone done with buf[cur^1]
    if (t < 11) {
      ISSUE_TILE((t + 1) * 64, cur ^ 1);
      SCHED0;
      asm volatile("s_waitcnt vmcnt(8)" ::: "memory");  // cur tile landed
    } else {
      asm volatile("s_waitcnt vmcnt(0)" ::: "memory");
    }
    SCHED0; BARRIER; SCHED0;      // all waves' et[cur] ready

    // ---- edge bias: row = lane, heads h0..h0+2 (wbT uniform -> s_load)
    const float* etr = &et[cur][lane << 7];
    float eb0 = 0.f, eb1 = 0.f, eb2 = 0.f;
#pragma unroll 8
    for (int k8 = 0; k8 < 32; ++k8) {
      const float4 e4 = *(const float4*)&etr[(k8 ^ rx) << 2];
      const float4 wa = *(const float4*)&wbT[(h0 + 0) * 128 + k8 * 4];
      const float4 wb = *(const float4*)&wbT[(h0 + 1) * 128 + k8 * 4];
      const float4 wc = *(const float4*)&wbT[(h0 + 2) * 128 + k8 * 4];
      eb0 += e4.x * wa.x + e4.y * wa.y + e4.z * wa.z + e4.w * wa.w;
      eb1 += e4.x * wb.x + e4.y * wb.y + e4.z * wb.z + e4.w * wb.w;
      eb2 += e4.x * wc.x + e4.y * wc.y + e4.z * wc.z + e4.w * wc.w;
    }
    const float ebv[3] = {eb0, eb1, eb2};

    // ---- logits
    const int j = t * 64 + lane;
    float lg[3];
#pragma unroll
    for (int u = 0; u < 3; ++u) {
      const int h = h0 + u;
      const float* sqp = sq + ((size_t)h * NN + i) * 16;   // uniform
      const float* skp = sk + ((size_t)h * NN + j) * 16;
      float dsk = 0.f;
#pragma unroll
      for (int k4 = 0; k4 < 4; ++k4) {
        const float4 a = *(const float4*)(sqp + k4 * 4);
        const float4 b = *(const float4*)(skp + k4 * 4);
        dsk += a.x * b.x + a.y * b.y + a.z * b.z + a.w * b.w;
      }
      const float* gkp = gk + ((size_t)h * NN + i) * 12;   // uniform
      const float* gqp = gq + ((size_t)h * NN + j) * 12;
      float dgq = 0.f;
#pragma unroll
      for (int k4 = 0; k4 < 3; ++k4) {
        const float4 a = *(const float4*)(gkp + k4 * 4);
        const float4 b = *(const float4*)(gqp + k4 * 4);
        dgq += a.x * b.x + a.y * b.y + a.z * b.z + a.w * b.w;
      }
      lg[u] = C1 * dsk + C2 * dgq
            - C3 * (ksq[(size_t)h * NN + i] + qsq[(size_t)h * NN + j])
            + S3 * ebv[u];
      logits[((size_t)h * NN + i) * NN + j] = lg[u];
    }

    // ---- defer-max online softmax (no per-tile reductions unless triggered)
#pragma unroll
    for (int u = 0; u < 3; ++u) {
      if (__any(lg[u] > mrun[u] + 6.f)) {
        float tm = lg[u];
#pragma unroll
        for (int off = 32; off; off >>= 1) tm = fmaxf(tm, __shfl_xor(tm, off, 64));
        const float mn = fmaxf(mrun[u], tm);
        const float f = __expf(mrun[u] - mn);
        Oa[u].x *= f; Oa[u].y *= f; Oa[u].z *= f; Oa[u].w *= f;
        lsum[u] *= f;
        mrun[u] = mn;
      }
      const float p = __expf(lg[u] - mrun[u]);
      lsum[u] += p;
      p_sh[h0 + u][lane & 1][lane >> 1] = p;
    }
    LGKM0; SCHED0;   // own wave's p_sh writes retired (wave-private columns)

    // ---- PV: lane owns (parity=half, d-quad=dq); rows 2s+half
#pragma unroll 2
    for (int sc = 0; sc < 8; ++sc) {
      const float4 pa = *(const float4*)&p_sh[h0 + 0][half][sc * 4];
      const float4 pb = *(const float4*)&p_sh[h0 + 1][half][sc * 4];
      const float4 pc = *(const float4*)&p_sh[h0 + 2][half][sc * 4];
#pragma unroll
      for (int q = 0; q < 4; ++q) {
        const int row = ((sc * 4 + q) << 1) | half;
        const float4 e4 = *(const float4*)&et[cur][(row << 7) + ((dq ^ (row & 7)) << 2)];
        const float p0 = q == 0 ? pa.x : q == 1 ? pa.y : q == 2 ? pa.z : pa.w;
        const float p1 = q == 0 ? pb.x : q == 1 ? pb.y : q == 2 ? pb.z : pb.w;
        const float p2 = q == 0 ? pc.x : q == 1 ? pc.y : q == 2 ? pc.z : pc.w;
        Oa[0].x += p0 * e4.x; Oa[0].y += p0 * e4.y; Oa[0].z += p0 * e4.z; Oa[0].w += p0 * e4.w;
        Oa[1].x += p1 * e4.x; Oa[1].y += p1 * e4.y; Oa[1].z += p1 * e4.z; Oa[1].w += p1 * e4.w;
        Oa[2].x += p2 * e4.x; Oa[2].y += p2 * e4.y; Oa[2].z += p2 * e4.z; Oa[2].w += p2 * e4.w;
      }
    }
  }
#undef ISSUE_TILE

  // ---- epilogue: reduce l over 64 lanes; Oa over parity partner
#pragma unroll
  for (int u = 0; u < 3; ++u) {
    float s = lsum[u];
#pragma unroll
    for (int off = 32; off; off >>= 1) s += __shfl_xor(s, off, 64);
    const float il = 1.0f / s;
    float4 o = Oa[u];
    o.x += __shfl_xor(o.x, 32, 64);
    o.y += __shfl_xor(o.y, 32, 64);
    o.z += __shfl_xor(o.z, 32, 64);
    o.w += __shfl_xor(o.w, 32, 64);
    if (half == 0) {
      o.x *= il; o.y *= il; o.z *= il; o.w *= il;
      *(float4*)&eout[(size_t)i * 1536 + (h0 + u) * 128 + dq * 4] = o;
    }
    if (lane == 0) {
      msm[(size_t)(h0 + u) * NN + i] = mrun[u];
      linv[(size_t)(h0 + u) * NN + i] = il;
    }
  }
}

// ---------------------------------------------------------------- k_scav ----
// scav[h][i][0..39] = sum_j exp(lg-m)*linv * V[h][j][0..39].
// Grid (48 i-tiles x 12 h), 320 thr. 16 rows/block; in-block j-split x4
// (js = tid/80), thread tile 4 rows (rg) x 2 cols (cp); LDS reduce over js.
__global__ __launch_bounds__(320) void k_scav(const float* __restrict__ logits,
    const float* __restrict__ msm, const float* __restrict__ linv,
    const float* __restrict__ V, float* __restrict__ scav) {
  __shared__ __align__(16) float At[64][20];   // [jj][16 rows, pad 20]
  __shared__ __align__(16) float Vt[64][40];
  __shared__ __align__(16) float red[320 * 8];
  const int i0 = blockIdx.x * 16;
  const int h  = blockIdx.y;
  const int tid = threadIdx.x;
  const int js = tid / 80, rem = tid % 80;
  const int rg = rem / 20, cp = rem % 20;
  float2 a0 = {0.f, 0.f}, a1 = {0.f, 0.f}, a2 = {0.f, 0.f}, a3 = {0.f, 0.f};
  for (int jt = 0; jt < 12; ++jt) {
    __syncthreads();
    for (int idx = tid; idx < 1024; idx += 320) {
      const int r = idx >> 6, jj = idx & 63;
      const size_t hi = (size_t)h * NN + i0 + r;
      const float lg = logits[hi * NN + jt * 64 + jj];
      At[jj][r] = __expf(lg - msm[hi]) * linv[hi];
    }
    for (int idx = tid; idx < 2560; idx += 320) {
      const int jj = idx / 40, c = idx % 40;
      Vt[jj][c] = V[((size_t)h * NN + jt * 64 + jj) * 40 + c];
    }
    __syncthreads();
#pragma unroll 4
    for (int s = 0; s < 16; ++s) {
      const int jj = js * 16 + s;
      const float4 a4 = *(const float4*)&At[jj][rg * 4];
      const float2 b2 = *(const float2*)&Vt[jj][cp * 2];
      a0.x += a4.x * b2.x; a0.y += a4.x * b2.y;
      a1.x += a4.y * b2.x; a1.y += a4.y * b2.y;
      a2.x += a4.z * b2.x; a2.y += a4.z * b2.y;
      a3.x += a4.w * b2.x; a3.y += a4.w * b2.y;
    }
  }
  __syncthreads();
  *(float4*)&red[tid * 8 + 0] = make_float4(a0.x, a0.y, a1.x, a1.y);
  *(float4*)&red[tid * 8 + 4] = make_float4(a2.x, a2.y, a3.x, a3.y);
  __syncthreads();
  if (tid < 80) {
    const int rg2 = tid / 20, cp2 = tid % 20;
    float4 s0 = make_float4(0.f, 0.f, 0.f, 0.f), s1 = s0;
#pragma unroll
    for (int q = 0; q < 4; ++q) {
      const float4 r0 = *(const float4*)&red[(tid + q * 80) * 8 + 0];
      const float4 r1 = *(const float4*)&red[(tid + q * 80) * 8 + 4];
      s0.x += r0.x; s0.y += r0.y; s0.z += r0.z; s0.w += r0.w;
      s1.x += r1.x; s1.y += r1.y; s1.z += r1.z; s1.w += r1.w;
    }
    const size_t base = (size_t)h * NN + i0 + rg2 * 4;
    *(float2*)&scav[(base + 0) * 40 + cp2 * 2] = make_float2(s0.x, s0.y);
    *(float2*)&scav[(base + 1) * 40 + cp2 * 2] = make_float2(s0.z, s0.w);
    *(float2*)&scav[(base + 2) * 40 + cp2 * 2] = make_float2(s1.x, s1.y);
    *(float2*)&scav[(base + 3) * 40 + cp2 * 2] = make_float2(s1.z, s1.w);
  }
}

// --------------------------------------------------------------- k_final ----
__global__ __launch_bounds__(256) void k_final(const float* __restrict__ node,
    const float* __restrict__ R, const float* __restrict__ t,
    const float* __restrict__ eout, const float* __restrict__ scav,
    const float* __restrict__ Wfin, const float* __restrict__ bfin,
    float* __restrict__ out) {
  const int i0 = blockIdx.x * 4;
  const int tid = threadIdx.x;
  __shared__ __align__(16) float comb[4][2112];
  __shared__ float rinv[4][9];
  __shared__ float tl[4][3];
  if (tid < 4) {
    const int i = i0 + tid;
    const float* Rn = R + i * 9;
    const float r00 = Rn[0], r01 = Rn[1], r02 = Rn[2];
    const float r10 = Rn[3], r11 = Rn[4], r12 = Rn[5];
    const float r20 = Rn[6], r21 = Rn[7], r22 = Rn[8];
    const float det = r00 * (r11 * r22 - r12 * r21)
                    - r01 * (r10 * r22 - r12 * r20)
                    + r02 * (r10 * r21 - r11 * r20);
    const float id = 1.0f / det;
    rinv[tid][0] = (r11 * r22 - r12 * r21) * id;
    rinv[tid][1] = (r02 * r21 - r01 * r22) * id;
    rinv[tid][2] = (r01 * r12 - r02 * r11) * id;
    rinv[tid][3] = (r12 * r20 - r10 * r22) * id;
    rinv[tid][4] = (r00 * r22 - r02 * r20) * id;
    rinv[tid][5] = (r02 * r10 - r00 * r12) * id;
    rinv[tid][6] = (r10 * r21 - r11 * r20) * id;
    rinv[tid][7] = (r01 * r20 - r00 * r21) * id;
    rinv[tid][8] = (r00 * r11 - r01 * r10) * id;
    tl[tid][0] = t[i * 3 + 0]; tl[tid][1] = t[i * 3 + 1]; tl[tid][2] = t[i * 3 + 2];
  }
  __syncthreads();
  for (int idx = tid; idx < 4 * 2112; idx += 256) {
    const int r = idx / 2112, k = idx % 2112;
    const int i = i0 + r;
    float val;
    if (k < 1536) {
      val = eout[(size_t)i * 1536 + k];
    } else if (k < 1728) {
      const int s = k - 1536, h = s >> 4, d = s & 15;
      val = scav[((size_t)h * NN + i) * 40 + d];
    } else if (k < 2016) {
      const int s = k - 1728, h = s / 24, rem = s % 24, p = rem / 3, x = rem % 3;
      const float* av = scav + ((size_t)h * NN + i) * 40 + 16 + p * 3;
      const float a0 = av[0] - tl[r][0], a1 = av[1] - tl[r][1], a2 = av[2] - tl[r][2];
      val = rinv[r][x * 3 + 0] * a0 + rinv[r][x * 3 + 1] * a1 + rinv[r][x * 3 + 2] * a2;
    } else {
      const int s = k - 2016, h = s >> 3, p = s & 7;
      const float* av = scav + ((size_t)h * NN + i) * 40 + 16 + p * 3;
      const float a0 = av[0] - tl[r][0], a1 = av[1] - tl[r][1], a2 = av[2] - tl[r][2];
      const float l0 = rinv[r][0] * a0 + rinv[r][1] * a1 + rinv[r][2] * a2;
      const float l1 = rinv[r][3] * a0 + rinv[r][4] * a1 + rinv[r][5] * a2;
      const float l2 = rinv[r][6] * a0 + rinv[r][7] * a1 + rinv[r][8] * a2;
      val = sqrtf(l0 * l0 + l1 * l1 + l2 * l2);
    }
    comb[r][k] = val;
  }
  __syncthreads();
  for (int c = tid; c < 384; c += 256) {
    float acc0 = bfin[c] + node[(size_t)(i0 + 0) * 384 + c];
    float acc1 = bfin[c] + node[(size_t)(i0 + 1) * 384 + c];
    float acc2 = bfin[c] + node[(size_t)(i0 + 2) * 384 + c];
    float acc3 = bfin[c] + node[(size_t)(i0 + 3) * 384 + c];
    for (int k4 = 0; k4 < 528; ++k4) {
      const int k = k4 * 4;
      const float w0 = Wfin[(size_t)(k + 0) * 384 + c];
      const float w1 = Wfin[(size_t)(k + 1) * 384 + c];
      const float w2 = Wfin[(size_t)(k + 2) * 384 + c];
      const float w3 = Wfin[(size_t)(k + 3) * 384 + c];
      const float4 c0v = *(const float4*)&comb[0][k];
      const float4 c1v = *(const float4*)&comb[1][k];
      const float4 c2v = *(const float4*)&comb[2][k];
      const float4 c3v = *(const float4*)&comb[3][k];
      acc0 += c0v.x * w0 + c0v.y * w1 + c0v.z * w2 + c0v.w * w3;
      acc1 += c1v.x * w0 + c1v.y * w1 + c1v.z * w2 + c1v.w * w3;
      acc2 += c2v.x * w0 + c2v.y * w1 + c2v.z * w2 + c2v.w * w3;
      acc3 += c3v.x * w0 + c3v.y * w1 + c3v.z * w2 + c3v.w * w3;
    }
    out[(size_t)(i0 + 0) * 384 + c] = acc0;
    out[(size_t)(i0 + 1) * 384 + c] = acc1;
    out[(size_t)(i0 + 2) * 384 + c] = acc2;
    out[(size_t)(i0 + 3) * 384 + c] = acc3;
  }
}

}  // namespace

extern "C" void kernel_launch(void* const* d_in, const int* in_sizes, int n_in,
                              void* d_out, int out_size, void* d_ws, size_t ws_size,
                              hipStream_t stream) {
  const float* node   = (const float*)d_in[0];
  const float* edge   = (const float*)d_in[1];
  const float* R      = (const float*)d_in[2];
  const float* t      = (const float*)d_in[3];
  const float* Wqkv   = (const float*)d_in[4];
  const float* Wvqk   = (const float*)d_in[5];
  const float* Wvv    = (const float*)d_in[6];
  const float* Webias = (const float*)d_in[7];
  const float* Wfin   = (const float*)d_in[8];
  const float* bfin   = (const float*)d_in[9];
  float* out = (float*)d_out;

  float* ws = (float*)d_ws;
  float* proj   = ws;                    // 884736
  float* sq     = proj   + 884736;       // 147456
  float* sk     = sq     + 147456;       // 147456
  float* gk     = sk     + 147456;       // 110592
  float* gq     = gk     + 110592;       // 110592
  float* ksq    = gq     + 110592;       // 9216
  float* qsq    = ksq    + 9216;         // 9216
  float* wbT    = qsq    + 9216;         // 1536
  float* V      = wbT    + 1536;         // 368640
  float* logits = V      + 368640;       // 7077888 (raw logits)
  float* eout   = logits + 7077888;      // 1179648
  float* scav   = eout   + 1179648;      // 368640
  float* msm    = scav   + 368640;       // 9216
  float* linv   = msm    + 9216;         // 9216

  hipLaunchKernelGGL(k_proj, dim3(192), dim3(288), 0, stream,
                     node, Wqkv, Wvqk, Wvv, proj);
  hipLaunchKernelGGL(k_geom, dim3(36), dim3(256), 0, stream,
                     proj, R, t, Webias, sq, sk, gk, gq, ksq, qsq, wbT, V);
  hipLaunchKernelGGL(k_fused, dim3(768), dim3(256), 0, stream,
                     edge, wbT, sq, sk, gk, gq, ksq, qsq, logits, eout, msm, linv);
  hipLaunchKernelGGL(k_scav, dim3(48, 12), dim3(320), 0, stream,
                     logits, msm, linv, V, scav);
  hipLaunchKernelGGL(k_final, dim3(192), dim3(256), 0, stream,
                     node, R, t, eout, scav, Wfin, bfin, out);
}

// Round 4
// 395.796 us; speedup vs baseline: 1.9212x; 1.1555x over previous
//
#include <hip/hip_runtime.h>
#include <cmath>

// InvariantPointAttention, N=768, H=12, D=16, NQP=4, NVP=8, NODE=384, EDGE=128.
// fp32. Flash-fused attention (32-row tiles, 4 blocks/CU) + K-split final GEMM.

namespace {

constexpr int NN = 768;
constexpr int NH = 12;

constexpr float S3 = 0.5773502691896258f;        // 3^-0.5
constexpr float C1 = 0.25f * S3;                 // (1/sqrt(16))/sqrt(3)
constexpr float C2 = 0.23570226039551584f * S3;  // 2*wc/sqrt(3)
constexpr float C3 = 0.11785113019775792f * S3;  // wc/sqrt(3)

#define LGKM0 asm volatile("s_waitcnt lgkmcnt(0)" ::: "memory")
#define SCHED0 __builtin_amdgcn_sched_barrier(0)
#define BARRIER __builtin_amdgcn_s_barrier()

// ---------------------------------------------------------------- k_proj ----
__global__ __launch_bounds__(288) void k_proj(const float* __restrict__ node,
    const float* __restrict__ Wqkv, const float* __restrict__ Wvqk,
    const float* __restrict__ Wvv, float* __restrict__ proj) {
  __shared__ __align__(16) float nl[4][384];
  const int i0 = blockIdx.x * 4;
  const int tid = threadIdx.x;
  for (int idx = tid; idx < 4 * 384; idx += 288)
    ((float*)nl)[idx] = node[(size_t)i0 * 384 + idx];
  __syncthreads();
  const int c0 = tid * 4;
  const float* W; int ld, col;
  if (c0 < 576)      { W = Wqkv; ld = 576; col = c0; }
  else if (c0 < 864) { W = Wvqk; ld = 288; col = c0 - 576; }
  else               { W = Wvv;  ld = 288; col = c0 - 864; }
  float4 acc[4];
#pragma unroll
  for (int r = 0; r < 4; ++r) acc[r] = make_float4(0.f, 0.f, 0.f, 0.f);
#pragma unroll 4
  for (int k = 0; k < 384; ++k) {
    const float4 w4 = *(const float4*)&W[(size_t)k * ld + col];
#pragma unroll
    for (int r = 0; r < 4; ++r) {
      const float nv = nl[r][k];
      acc[r].x += nv * w4.x; acc[r].y += nv * w4.y;
      acc[r].z += nv * w4.z; acc[r].w += nv * w4.w;
    }
  }
#pragma unroll
  for (int r = 0; r < 4; ++r)
    *(float4*)&proj[(size_t)(i0 + r) * 1152 + c0] = acc[r];
}

// ---------------------------------------------------------------- k_geom ----
__global__ __launch_bounds__(256) void k_geom(const float* __restrict__ proj,
    const float* __restrict__ R, const float* __restrict__ t,
    const float* __restrict__ Webias,
    float* __restrict__ sq, float* __restrict__ sk,
    float* __restrict__ gk, float* __restrict__ gq,
    float* __restrict__ ksq, float* __restrict__ qsq,
    float* __restrict__ wbT, float* __restrict__ V) {
  const int gid = blockIdx.x * 256 + threadIdx.x;
  if (gid < 128 * 12) {
    const int d = gid / 12, h = gid % 12;
    wbT[h * 128 + d] = Webias[gid];
  }
  if (gid >= NN * NH) return;
  const int n = gid / NH, h = gid % NH;
  const float* pr = proj + (size_t)n * 1152;
  const float* Rn = R + n * 9;
  const float t0 = t[n * 3 + 0], t1 = t[n * 3 + 1], t2 = t[n * 3 + 2];
  const size_t hn = (size_t)h * NN + n;
#pragma unroll
  for (int d = 0; d < 16; ++d) {
    sq[hn * 16 + d] = pr[h * 16 + d];
    sk[hn * 16 + d] = pr[(12 + h) * 16 + d];
    V[hn * 40 + d]  = pr[(24 + h) * 16 + d];
  }
  float qs = 0.f, ks = 0.f;
#pragma unroll
  for (int p = 0; p < 4; ++p) {
    {
      const float vx = pr[576 + (h * 4 + p) * 3 + 0];
      const float vy = pr[576 + (h * 4 + p) * 3 + 1];
      const float vz = pr[576 + (h * 4 + p) * 3 + 2];
      const float g0 = Rn[0] * vx + Rn[1] * vy + Rn[2] * vz + t0;
      const float g1 = Rn[3] * vx + Rn[4] * vy + Rn[5] * vz + t1;
      const float g2 = Rn[6] * vx + Rn[7] * vy + Rn[8] * vz + t2;
      gq[hn * 12 + p * 3 + 0] = g0; gq[hn * 12 + p * 3 + 1] = g1;
      gq[hn * 12 + p * 3 + 2] = g2;
      qs += g0 * g0 + g1 * g1 + g2 * g2;
    }
    {
      const float vx = pr[576 + ((12 + h) * 4 + p) * 3 + 0];
      const float vy = pr[576 + ((12 + h) * 4 + p) * 3 + 1];
      const float vz = pr[576 + ((12 + h) * 4 + p) * 3 + 2];
      const float g0 = Rn[0] * vx + Rn[1] * vy + Rn[2] * vz + t0;
      const float g1 = Rn[3] * vx + Rn[4] * vy + Rn[5] * vz + t1;
      const float g2 = Rn[6] * vx + Rn[7] * vy + Rn[8] * vz + t2;
      gk[hn * 12 + p * 3 + 0] = g0; gk[hn * 12 + p * 3 + 1] = g1;
      gk[hn * 12 + p * 3 + 2] = g2;
      ks += g0 * g0 + g1 * g1 + g2 * g2;
    }
  }
  qsq[hn] = qs;
  ksq[hn] = ks;
#pragma unroll
  for (int p = 0; p < 8; ++p) {
    const float vx = pr[864 + (h * 8 + p) * 3 + 0];
    const float vy = pr[864 + (h * 8 + p) * 3 + 1];
    const float vz = pr[864 + (h * 8 + p) * 3 + 2];
    V[hn * 40 + 16 + p * 3 + 0] = Rn[0] * vx + Rn[1] * vy + Rn[2] * vz + t0;
    V[hn * 40 + 16 + p * 3 + 1] = Rn[3] * vx + Rn[4] * vy + Rn[5] * vz + t1;
    V[hn * 40 + 16 + p * 3 + 2] = Rn[6] * vx + Rn[7] * vy + Rn[8] * vz + t2;
  }
}

// --------------------------------------------------------------- k_fused ----
// One block per i. 24 tiles of 32 rows; global_load_lds dbuf, counted vmcnt.
// Wave w: heads 3w..3w+2. Lane = (half = lane>>5, r32 = lane&31).
// eb: lane (row=r32, k-half); logits: j = t*32+r32 (dup across halves);
// PV: lane (row-parity=half, colquad=r32).
__global__ __launch_bounds__(256, 4) void k_fused(
    const float* __restrict__ edge, const float* __restrict__ wbT,
    const float* __restrict__ sq, const float* __restrict__ sk,
    const float* __restrict__ gk, const float* __restrict__ gq,
    const float* __restrict__ ksq, const float* __restrict__ qsq,
    float* __restrict__ logits, float* __restrict__ eout,
    float* __restrict__ msm, float* __restrict__ linv) {
  __shared__ __align__(16) float et[2][32 * 128];   // 32 KB dbuf
  __shared__ __align__(16) float wb_lds[12 * 128];  // 6 KB
  __shared__ __align__(16) float p_sh[12][2][16];   // 1.5 KB
  const int i = blockIdx.x;
  const int tid = threadIdx.x;
  const int lane = tid & 63;
  const int w = __builtin_amdgcn_readfirstlane(tid >> 6);
  const int h0 = w * 3;
  const int half = lane >> 5;
  const int r32 = lane & 31;
  const int rx = r32 & 7;

  for (int idx = tid; idx < 1536; idx += 256) wb_lds[idx] = wbT[idx];
  LGKM0;

#define ISSUE_TILE(jb, bufidx) do {                                           \
    _Pragma("unroll")                                                         \
    for (int q = 0; q < 4; ++q) {                                             \
      const int rl = w * 8 + q * 2 + half;                                    \
      const int blk = r32 ^ (rl & 7);                                         \
      const float* gp = edge + ((size_t)i * NN + (jb) + rl) * 128 + (blk << 2); \
      float* lp = &et[bufidx][(w * 4 + q) * 256];                             \
      __builtin_amdgcn_global_load_lds(                                       \
          (const __attribute__((address_space(1))) void*)gp,                  \
          (__attribute__((address_space(3))) void*)lp, 16, 0, 0);             \
    }                                                                         \
  } while (0)

  float mrun[3] = {-3.0e38f, -3.0e38f, -3.0e38f};
  float lsum[3] = {0.f, 0.f, 0.f};
  float4 Oa[3];
#pragma unroll
  for (int u = 0; u < 3; ++u) Oa[u] = make_float4(0.f, 0.f, 0.f, 0.f);

  ISSUE_TILE(0, 0);

  for (int t = 0; t < 24; ++t) {
    const int cur = t & 1;
    SCHED0; BARRIER; SCHED0;        // everyone done with buf[cur^1]
    if (t < 23) {
      ISSUE_TILE((t + 1) * 32, cur ^ 1);
      SCHED0;
      asm volatile("s_waitcnt vmcnt(4)" ::: "memory");  // cur tile landed
    } else {
      asm volatile("s_waitcnt vmcnt(0)" ::: "memory");
    }
    SCHED0; BARRIER; SCHED0;        // all waves' et[cur] ready

    // ---- edge bias: row r32, k-half per lane; cross-half combine after.
    const float* etr = &et[cur][r32 << 7];
    const int kbase = half << 4;
    float eb0 = 0.f, eb1 = 0.f, eb2 = 0.f;
#pragma unroll
    for (int k16 = 0; k16 < 16; ++k16) {
      const int k8 = kbase + k16;
      const float4 e4 = *(const float4*)&etr[(k8 ^ rx) << 2];
      const float4 wa = *(const float4*)&wb_lds[(h0 + 0) * 128 + k8 * 4];
      const float4 wb = *(const float4*)&wb_lds[(h0 + 1) * 128 + k8 * 4];
      const float4 wc = *(const float4*)&wb_lds[(h0 + 2) * 128 + k8 * 4];
      eb0 += e4.x * wa.x + e4.y * wa.y + e4.z * wa.z + e4.w * wa.w;
      eb1 += e4.x * wb.x + e4.y * wb.y + e4.z * wb.z + e4.w * wb.w;
      eb2 += e4.x * wc.x + e4.y * wc.y + e4.z * wc.z + e4.w * wc.w;
    }
    eb0 += __shfl_xor(eb0, 32, 64);
    eb1 += __shfl_xor(eb1, 32, 64);
    eb2 += __shfl_xor(eb2, 32, 64);
    const float ebv[3] = {eb0, eb1, eb2};

    // ---- logits (computed identically by both halves)
    const int j = t * 32 + r32;
    float lg[3];
#pragma unroll
    for (int u = 0; u < 3; ++u) {
      const int h = h0 + u;
      const float* sqp = sq + ((size_t)h * NN + i) * 16;   // uniform
      const float* skp = sk + ((size_t)h * NN + j) * 16;
      float dsk = 0.f;
#pragma unroll
      for (int k4 = 0; k4 < 4; ++k4) {
        const float4 a = *(const float4*)(sqp + k4 * 4);
        const float4 b = *(const float4*)(skp + k4 * 4);
        dsk += a.x * b.x + a.y * b.y + a.z * b.z + a.w * b.w;
      }
      const float* gkp = gk + ((size_t)h * NN + i) * 12;   // uniform
      const float* gqp = gq + ((size_t)h * NN + j) * 12;
      float dgq = 0.f;
#pragma unroll
      for (int k4 = 0; k4 < 3; ++k4) {
        const float4 a = *(const float4*)(gkp + k4 * 4);
        const float4 b = *(const float4*)(gqp + k4 * 4);
        dgq += a.x * b.x + a.y * b.y + a.z * b.z + a.w * b.w;
      }
      lg[u] = C1 * dsk + C2 * dgq
            - C3 * (ksq[(size_t)h * NN + i] + qsq[(size_t)h * NN + j])
            + S3 * ebv[u];
      if (half == 0) logits[((size_t)h * NN + i) * NN + j] = lg[u];
    }

    // ---- defer-max online softmax
#pragma unroll
    for (int u = 0; u < 3; ++u) {
      if (__any(lg[u] > mrun[u] + 6.f)) {
        float tm = lg[u];
#pragma unroll
        for (int off = 16; off; off >>= 1) tm = fmaxf(tm, __shfl_xor(tm, off, 64));
        const float mn = fmaxf(mrun[u], tm);
        const float f = __expf(mrun[u] - mn);
        Oa[u].x *= f; Oa[u].y *= f; Oa[u].z *= f; Oa[u].w *= f;
        lsum[u] *= f;
        mrun[u] = mn;
      }
      const float p = __expf(lg[u] - mrun[u]);
      lsum[u] += p;
      if (half == 0) p_sh[h0 + u][r32 & 1][r32 >> 1] = p;
    }
    LGKM0; SCHED0;   // own wave's p_sh writes retired (intra-wave consumer)

    // ---- PV: lane (parity=half, colquad=r32); rows 2s+half
#pragma unroll
    for (int sc = 0; sc < 4; ++sc) {
      const float4 pa = *(const float4*)&p_sh[h0 + 0][half][sc * 4];
      const float4 pb = *(const float4*)&p_sh[h0 + 1][half][sc * 4];
      const float4 pc = *(const float4*)&p_sh[h0 + 2][half][sc * 4];
#pragma unroll
      for (int q = 0; q < 4; ++q) {
        const int row = ((sc * 4 + q) << 1) | half;
        const float4 e4 = *(const float4*)&et[cur][(row << 7) + ((r32 ^ (row & 7)) << 2)];
        const float p0 = q == 0 ? pa.x : q == 1 ? pa.y : q == 2 ? pa.z : pa.w;
        const float p1 = q == 0 ? pb.x : q == 1 ? pb.y : q == 2 ? pb.z : pb.w;
        const float p2 = q == 0 ? pc.x : q == 1 ? pc.y : q == 2 ? pc.z : pc.w;
        Oa[0].x += p0 * e4.x; Oa[0].y += p0 * e4.y; Oa[0].z += p0 * e4.z; Oa[0].w += p0 * e4.w;
        Oa[1].x += p1 * e4.x; Oa[1].y += p1 * e4.y; Oa[1].z += p1 * e4.z; Oa[1].w += p1 * e4.w;
        Oa[2].x += p2 * e4.x; Oa[2].y += p2 * e4.y; Oa[2].z += p2 * e4.z; Oa[2].w += p2 * e4.w;
      }
    }
  }
#undef ISSUE_TILE

  // ---- epilogue
#pragma unroll
  for (int u = 0; u < 3; ++u) {
    float s = lsum[u];
#pragma unroll
    for (int off = 16; off; off >>= 1) s += __shfl_xor(s, off, 64);
    const float il = 1.0f / s;
    float4 o = Oa[u];
    o.x += __shfl_xor(o.x, 32, 64);
    o.y += __shfl_xor(o.y, 32, 64);
    o.z += __shfl_xor(o.z, 32, 64);
    o.w += __shfl_xor(o.w, 32, 64);
    if (half == 0) {
      o.x *= il; o.y *= il; o.z *= il; o.w *= il;
      *(float4*)&eout[(size_t)i * 1536 + (h0 + u) * 128 + r32 * 4] = o;
    }
    if (lane == 0) {
      msm[(size_t)(h0 + u) * NN + i] = mrun[u];
      linv[(size_t)(h0 + u) * NN + i] = il;
    }
  }
}

// ---------------------------------------------------------------- k_scav ----
__global__ __launch_bounds__(320) void k_scav(const float* __restrict__ logits,
    const float* __restrict__ msm, const float* __restrict__ linv,
    const float* __restrict__ V, float* __restrict__ scav) {
  __shared__ __align__(16) float At[64][20];
  __shared__ __align__(16) float Vt[64][40];
  __shared__ __align__(16) float red[320 * 8];
  const int i0 = blockIdx.x * 16;
  const int h  = blockIdx.y;
  const int tid = threadIdx.x;
  const int js = tid / 80, rem = tid % 80;
  const int rg = rem / 20, cp = rem % 20;
  float2 a0 = {0.f, 0.f}, a1 = {0.f, 0.f}, a2 = {0.f, 0.f}, a3 = {0.f, 0.f};
  for (int jt = 0; jt < 12; ++jt) {
    __syncthreads();
    for (int idx = tid; idx < 1024; idx += 320) {
      const int r = idx >> 6, jj = idx & 63;
      const size_t hi = (size_t)h * NN + i0 + r;
      const float lg = logits[hi * NN + jt * 64 + jj];
      At[jj][r] = __expf(lg - msm[hi]) * linv[hi];
    }
    for (int idx = tid; idx < 2560; idx += 320) {
      const int jj = idx / 40, c = idx % 40;
      Vt[jj][c] = V[((size_t)h * NN + jt * 64 + jj) * 40 + c];
    }
    __syncthreads();
#pragma unroll 4
    for (int s = 0; s < 16; ++s) {
      const int jj = js * 16 + s;
      const float4 a4 = *(const float4*)&At[jj][rg * 4];
      const float2 b2 = *(const float2*)&Vt[jj][cp * 2];
      a0.x += a4.x * b2.x; a0.y += a4.x * b2.y;
      a1.x += a4.y * b2.x; a1.y += a4.y * b2.y;
      a2.x += a4.z * b2.x; a2.y += a4.z * b2.y;
      a3.x += a4.w * b2.x; a3.y += a4.w * b2.y;
    }
  }
  __syncthreads();
  *(float4*)&red[tid * 8 + 0] = make_float4(a0.x, a0.y, a1.x, a1.y);
  *(float4*)&red[tid * 8 + 4] = make_float4(a2.x, a2.y, a3.x, a3.y);
  __syncthreads();
  if (tid < 80) {
    const int rg2 = tid / 20, cp2 = tid % 20;
    float4 s0 = make_float4(0.f, 0.f, 0.f, 0.f), s1 = s0;
#pragma unroll
    for (int q = 0; q < 4; ++q) {
      const float4 r0 = *(const float4*)&red[(tid + q * 80) * 8 + 0];
      const float4 r1 = *(const float4*)&red[(tid + q * 80) * 8 + 4];
      s0.x += r0.x; s0.y += r0.y; s0.z += r0.z; s0.w += r0.w;
      s1.x += r1.x; s1.y += r1.y; s1.z += r1.z; s1.w += r1.w;
    }
    const size_t base = (size_t)h * NN + i0 + rg2 * 4;
    *(float2*)&scav[(base + 0) * 40 + cp2 * 2] = make_float2(s0.x, s0.y);
    *(float2*)&scav[(base + 1) * 40 + cp2 * 2] = make_float2(s0.z, s0.w);
    *(float2*)&scav[(base + 2) * 40 + cp2 * 2] = make_float2(s1.x, s1.y);
    *(float2*)&scav[(base + 3) * 40 + cp2 * 2] = make_float2(s1.z, s1.w);
  }
}

// ---------------------------------------------------------------- k_comb ----
// Build comb[768][2112] = [edge_out | scalar_out | local_v | v_len].
__global__ __launch_bounds__(256) void k_comb(
    const float* __restrict__ R, const float* __restrict__ t,
    const float* __restrict__ eout, const float* __restrict__ scav,
    float* __restrict__ comb) {
  const int i0 = blockIdx.x * 4;
  const int tid = threadIdx.x;
  __shared__ float rinv[4][9];
  __shared__ float tl[4][3];
  if (tid < 4) {
    const int i = i0 + tid;
    const float* Rn = R + i * 9;
    const float r00 = Rn[0], r01 = Rn[1], r02 = Rn[2];
    const float r10 = Rn[3], r11 = Rn[4], r12 = Rn[5];
    const float r20 = Rn[6], r21 = Rn[7], r22 = Rn[8];
    const float det = r00 * (r11 * r22 - r12 * r21)
                    - r01 * (r10 * r22 - r12 * r20)
                    + r02 * (r10 * r21 - r11 * r20);
    const float id = 1.0f / det;
    rinv[tid][0] = (r11 * r22 - r12 * r21) * id;
    rinv[tid][1] = (r02 * r21 - r01 * r22) * id;
    rinv[tid][2] = (r01 * r12 - r02 * r11) * id;
    rinv[tid][3] = (r12 * r20 - r10 * r22) * id;
    rinv[tid][4] = (r00 * r22 - r02 * r20) * id;
    rinv[tid][5] = (r02 * r10 - r00 * r12) * id;
    rinv[tid][6] = (r10 * r21 - r11 * r20) * id;
    rinv[tid][7] = (r01 * r20 - r00 * r21) * id;
    rinv[tid][8] = (r00 * r11 - r01 * r10) * id;
    tl[tid][0] = t[i * 3 + 0]; tl[tid][1] = t[i * 3 + 1]; tl[tid][2] = t[i * 3 + 2];
  }
  __syncthreads();
  for (int idx = tid; idx < 4 * 2112; idx += 256) {
    const int r = idx / 2112, k = idx % 2112;
    const int i = i0 + r;
    float val;
    if (k < 1536) {
      val = eout[(size_t)i * 1536 + k];
    } else if (k < 1728) {
      const int s = k - 1536, h = s >> 4, d = s & 15;
      val = scav[((size_t)h * NN + i) * 40 + d];
    } else if (k < 2016) {
      const int s = k - 1728, h = s / 24, rem = s % 24, p = rem / 3, x = rem % 3;
      const float* av = scav + ((size_t)h * NN + i) * 40 + 16 + p * 3;
      const float a0 = av[0] - tl[r][0], a1 = av[1] - tl[r][1], a2 = av[2] - tl[r][2];
      val = rinv[r][x * 3 + 0] * a0 + rinv[r][x * 3 + 1] * a1 + rinv[r][x * 3 + 2] * a2;
    } else {
      const int s = k - 2016, h = s >> 3, p = s & 7;
      const float* av = scav + ((size_t)h * NN + i) * 40 + 16 + p * 3;
      const float a0 = av[0] - tl[r][0], a1 = av[1] - tl[r][1], a2 = av[2] - tl[r][2];
      const float l0 = rinv[r][0] * a0 + rinv[r][1] * a1 + rinv[r][2] * a2;
      const float l1 = rinv[r][3] * a0 + rinv[r][4] * a1 + rinv[r][5] * a2;
      const float l2 = rinv[r][6] * a0 + rinv[r][7] * a1 + rinv[r][8] * a2;
      val = sqrtf(l0 * l0 + l1 * l1 + l2 * l2);
    }
    comb[(size_t)i * 2112 + k] = val;
  }
}

// -------------------------------------------------------------- k_finalA ----
// partial[ks][768][384]: 64x64 tile GEMM, K-chunk 352 (11 subtiles of 32).
// Thread: 4 rows x 4 cols.
__global__ __launch_bounds__(256) void k_finalA(
    const float* __restrict__ comb, const float* __restrict__ Wfin,
    float* __restrict__ partial) {
  __shared__ __align__(16) float cl[64][36];
  __shared__ __align__(16) float wl[32][68];
  const int i0 = blockIdx.x * 64;
  const int c0 = blockIdx.y * 64;
  const int k0 = blockIdx.z * 352;
  const int tid = threadIdx.x;
  const int cq = tid & 15, rq = tid >> 4;
  float4 acc[4];
#pragma unroll
  for (int r = 0; r < 4; ++r) acc[r] = make_float4(0.f, 0.f, 0.f, 0.f);
  for (int sub = 0; sub < 11; ++sub) {
    const int kc = k0 + sub * 32;
    __syncthreads();
#pragma unroll
    for (int half = 0; half < 2; ++half) {
      const int qi = tid + half * 256;
      const int r = qi >> 3, kq = qi & 7;
      *(float4*)&cl[r][kq * 4] = *(const float4*)&comb[(size_t)(i0 + r) * 2112 + kc + kq * 4];
      const int kk = qi >> 4, cc = qi & 15;
      *(float4*)&wl[kk][cc * 4] = *(const float4*)&Wfin[(size_t)(kc + kk) * 384 + c0 + cc * 4];
    }
    __syncthreads();
#pragma unroll
    for (int k4 = 0; k4 < 8; ++k4) {
      float4 a[4], wv[4];
#pragma unroll
      for (int r = 0; r < 4; ++r) a[r] = *(const float4*)&cl[rq * 4 + r][k4 * 4];
#pragma unroll
      for (int q = 0; q < 4; ++q) wv[q] = *(const float4*)&wl[k4 * 4 + q][cq * 4];
#pragma unroll
      for (int r = 0; r < 4; ++r) {
        acc[r].x += a[r].x * wv[0].x + a[r].y * wv[1].x + a[r].z * wv[2].x + a[r].w * wv[3].x;
        acc[r].y += a[r].x * wv[0].y + a[r].y * wv[1].y + a[r].z * wv[2].y + a[r].w * wv[3].y;
        acc[r].z += a[r].x * wv[0].z + a[r].y * wv[1].z + a[r].z * wv[2].z + a[r].w * wv[3].z;
        acc[r].w += a[r].x * wv[0].w + a[r].y * wv[1].w + a[r].z * wv[2].w + a[r].w * wv[3].w;
      }
    }
  }
#pragma unroll
  for (int r = 0; r < 4; ++r)
    *(float4*)&partial[((size_t)blockIdx.z * NN + i0 + rq * 4 + r) * 384 + c0 + cq * 4] = acc[r];
}

// -------------------------------------------------------------- k_finalB ----
__global__ __launch_bounds__(256) void k_finalB(const float* __restrict__ node,
    const float* __restrict__ partial, const float* __restrict__ bfin,
    float* __restrict__ out) {
  const int gid = blockIdx.x * 256 + threadIdx.x;   // 73728 quads
  const int i = gid / 96, cq = gid % 96;
  float4 v = *(const float4*)&node[(size_t)i * 384 + cq * 4];
  const float4 b = *(const float4*)&bfin[cq * 4];
  v.x += b.x; v.y += b.y; v.z += b.z; v.w += b.w;
#pragma unroll
  for (int s = 0; s < 6; ++s) {
    const float4 p = *(const float4*)&partial[((size_t)s * NN + i) * 384 + cq * 4];
    v.x += p.x; v.y += p.y; v.z += p.z; v.w += p.w;
  }
  *(float4*)&out[(size_t)i * 384 + cq * 4] = v;
}

}  // namespace

extern "C" void kernel_launch(void* const* d_in, const int* in_sizes, int n_in,
                              void* d_out, int out_size, void* d_ws, size_t ws_size,
                              hipStream_t stream) {
  const float* node   = (const float*)d_in[0];
  const float* edge   = (const float*)d_in[1];
  const float* R      = (const float*)d_in[2];
  const float* t      = (const float*)d_in[3];
  const float* Wqkv   = (const float*)d_in[4];
  const float* Wvqk   = (const float*)d_in[5];
  const float* Wvv    = (const float*)d_in[6];
  const float* Webias = (const float*)d_in[7];
  const float* Wfin   = (const float*)d_in[8];
  const float* bfin   = (const float*)d_in[9];
  float* out = (float*)d_out;

  float* ws = (float*)d_ws;
  float* proj   = ws;                    // 884736
  float* sq     = proj   + 884736;       // 147456
  float* sk     = sq     + 147456;       // 147456
  float* gk     = sk     + 147456;       // 110592
  float* gq     = gk     + 110592;       // 110592
  float* ksq    = gq     + 110592;       // 9216
  float* qsq    = ksq    + 9216;         // 9216
  float* wbT    = qsq    + 9216;         // 1536
  float* V      = wbT    + 1536;         // 368640
  float* logits = V      + 368640;       // 7077888 (raw logits)
  float* eout   = logits + 7077888;      // 1179648
  float* scav   = eout   + 1179648;      // 368640
  float* msm    = scav   + 368640;       // 9216
  float* linv   = msm    + 9216;         // 9216
  // comb/partial alias the logits region (dead after k_scav):
  float* comb    = logits;               // 768*2112  = 1622016
  float* partial = logits + 1622016;     // 6*768*384 = 1769472 (fits in 7077888)

  hipLaunchKernelGGL(k_proj, dim3(192), dim3(288), 0, stream,
                     node, Wqkv, Wvqk, Wvv, proj);
  hipLaunchKernelGGL(k_geom, dim3(36), dim3(256), 0, stream,
                     proj, R, t, Webias, sq, sk, gk, gq, ksq, qsq, wbT, V);
  hipLaunchKernelGGL(k_fused, dim3(768), dim3(256), 0, stream,
                     edge, wbT, sq, sk, gk, gq, ksq, qsq, logits, eout, msm, linv);
  hipLaunchKernelGGL(k_scav, dim3(48, 12), dim3(320), 0, stream,
                     logits, msm, linv, V, scav);
  hipLaunchKernelGGL(k_comb, dim3(192), dim3(256), 0, stream,
                     R, t, eout, scav, comb);
  hipLaunchKernelGGL(k_finalA, dim3(12, 6, 6), dim3(256), 0, stream,
                     comb, Wfin, partial);
  hipLaunchKernelGGL(k_finalB, dim3(288), dim3(256), 0, stream,
                     node, partial, bfin, out);
}